// Round 1
// baseline (4256.908 us; speedup 1.0000x reference)
//
#include <hip/hip_runtime.h>
#include <math.h>

#define N_NODES 100000
#define N_EDGES 600000
#define HIDDEN 128
#define EDGE_CH 4
#define NUM_LAYERS 3

// Layout: x buffer = d_out (first N_NODES*HIDDEN floats).
//         agg buffer = d_ws  (N_NODES*HIDDEN floats = 51.2 MB).
// batch_vec written as float into d_out + N_NODES*HIDDEN.

// x = emb[z]; agg = x  (agg init includes the (1+eps)*x term, eps=0)
__global__ void embed_init_kernel(const float* __restrict__ emb,
                                  const int* __restrict__ z,
                                  float* __restrict__ x,
                                  float* __restrict__ agg) {
    int t = blockIdx.x * blockDim.x + threadIdx.x;   // N_NODES*32 threads exactly
    int node = t >> 5;
    int c4 = t & 31;
    if (node < N_NODES) {
        float4 v = ((const float4*)(emb + (size_t)z[node] * HIDDEN))[c4];
        ((float4*)(x + (size_t)node * HIDDEN))[c4] = v;
        ((float4*)(agg + (size_t)node * HIDDEN))[c4] = v;
    }
}

// For each edge: m = relu(x[src] + edge_attr@We + be); atomicAdd into agg[dst].
// 32 lanes (float4 each) per edge, 8 edges per 256-thread block.
__global__ void edge_kernel(const float* __restrict__ x,
                            const float* __restrict__ edge_attr,
                            const int* __restrict__ src,
                            const int* __restrict__ dst,
                            const float* __restrict__ We_l,   // [4][128]
                            const float* __restrict__ be_l,   // [128]
                            float* __restrict__ agg) {
    __shared__ float sWe[EDGE_CH * HIDDEN];
    __shared__ float sbe[HIDDEN];
    for (int i = threadIdx.x; i < EDGE_CH * HIDDEN; i += blockDim.x) sWe[i] = We_l[i];
    if (threadIdx.x < HIDDEN) sbe[threadIdx.x] = be_l[threadIdx.x];
    __syncthreads();

    int t = blockIdx.x * blockDim.x + threadIdx.x;
    int e = t >> 5;
    if (e >= N_EDGES) return;
    int c4 = t & 31;

    int s = src[e];
    int d = dst[e];
    float4 ea = ((const float4*)edge_attr)[e];          // 4 edge channels, broadcast
    float4 w0 = ((const float4*)sWe)[0 * 32 + c4];
    float4 w1 = ((const float4*)sWe)[1 * 32 + c4];
    float4 w2 = ((const float4*)sWe)[2 * 32 + c4];
    float4 w3 = ((const float4*)sWe)[3 * 32 + c4];
    float4 bb = ((const float4*)sbe)[c4];
    float4 xv = ((const float4*)(x + (size_t)s * HIDDEN))[c4];

    float m0 = xv.x + ea.x * w0.x + ea.y * w1.x + ea.z * w2.x + ea.w * w3.x + bb.x;
    float m1 = xv.y + ea.x * w0.y + ea.y * w1.y + ea.z * w2.y + ea.w * w3.y + bb.y;
    float m2 = xv.z + ea.x * w0.z + ea.y * w1.z + ea.z * w2.z + ea.w * w3.z + bb.z;
    float m3 = xv.w + ea.x * w0.w + ea.y * w1.w + ea.z * w2.w + ea.w * w3.w + bb.w;

    float* ap = agg + (size_t)d * HIDDEN + c4 * 4;
    atomicAdd(ap + 0, fmaxf(m0, 0.f));
    atomicAdd(ap + 1, fmaxf(m1, 0.f));
    atomicAdd(ap + 2, fmaxf(m2, 0.f));
    atomicAdd(ap + 3, fmaxf(m3, 0.f));
}

// x_new = silu(h@W1 + b1)@W2 + b2, h = agg. 8 nodes per 256-thread block.
// Also re-inits agg = x_new for the next layer (except after last layer).
__global__ void mlp_kernel(const float* __restrict__ h,
                           const float* __restrict__ W1, const float* __restrict__ b1,
                           const float* __restrict__ W2, const float* __restrict__ b2,
                           float* __restrict__ x, float* __restrict__ agg_out,
                           int write_agg) {
    __shared__ float hs[8 * HIDDEN];
    __shared__ float ts[8 * HIDDEN];
    int row = threadIdx.x >> 5;
    int c4 = threadIdx.x & 31;
    int node0 = blockIdx.x * 8;
    int node = node0 + row;

    // stage 8 h-rows (exactly 256 float4)
    ((float4*)hs)[threadIdx.x] = ((const float4*)(h + (size_t)node0 * HIDDEN))[threadIdx.x];
    __syncthreads();

    float4 acc = ((const float4*)b1)[c4];
    const float* hrow = hs + row * HIDDEN;
    #pragma unroll 8
    for (int k = 0; k < HIDDEN; k++) {
        float hk = hrow[k];
        float4 w = ((const float4*)(W1 + (size_t)k * HIDDEN))[c4];
        acc.x += hk * w.x; acc.y += hk * w.y; acc.z += hk * w.z; acc.w += hk * w.w;
    }
    // silu
    acc.x = acc.x / (1.f + __expf(-acc.x));
    acc.y = acc.y / (1.f + __expf(-acc.y));
    acc.z = acc.z / (1.f + __expf(-acc.z));
    acc.w = acc.w / (1.f + __expf(-acc.w));
    ((float4*)(ts + row * HIDDEN))[c4] = acc;
    __syncthreads();

    float4 o = ((const float4*)b2)[c4];
    const float* trow = ts + row * HIDDEN;
    #pragma unroll 8
    for (int k = 0; k < HIDDEN; k++) {
        float tk = trow[k];
        float4 w = ((const float4*)(W2 + (size_t)k * HIDDEN))[c4];
        o.x += tk * w.x; o.y += tk * w.y; o.z += tk * w.z; o.w += tk * w.w;
    }
    ((float4*)(x + (size_t)node * HIDDEN))[c4] = o;
    if (write_agg)
        ((float4*)(agg_out + (size_t)node * HIDDEN))[c4] = o;
}

__global__ void batch_out_kernel(const int* __restrict__ bv, float* __restrict__ out) {
    int i = blockIdx.x * blockDim.x + threadIdx.x;
    if (i < N_NODES) out[i] = (float)bv[i];
}

extern "C" void kernel_launch(void* const* d_in, const int* in_sizes, int n_in,
                              void* d_out, int out_size, void* d_ws, size_t ws_size,
                              hipStream_t stream) {
    const float* emb       = (const float*)d_in[0];
    const float* We        = (const float*)d_in[1];
    const float* be        = (const float*)d_in[2];
    const float* W1        = (const float*)d_in[3];
    const float* b1        = (const float*)d_in[4];
    const float* W2        = (const float*)d_in[5];
    const float* b2        = (const float*)d_in[6];
    const float* edge_attr = (const float*)d_in[7];
    const int*   z         = (const int*)d_in[8];
    const int*   ei        = (const int*)d_in[9];
    const int*   bv        = (const int*)d_in[10];

    float* x   = (float*)d_out;                 // N_NODES*HIDDEN
    float* agg = (float*)d_ws;                  // N_NODES*HIDDEN
    const int* src = ei;
    const int* dst = ei + N_EDGES;

    // x = emb[z]; agg = x
    embed_init_kernel<<<(N_NODES * 32) / 256, 256, 0, stream>>>(emb, z, x, agg);

    for (int l = 0; l < NUM_LAYERS; l++) {
        edge_kernel<<<(N_EDGES * 32) / 256, 256, 0, stream>>>(
            x, edge_attr, src, dst,
            We + (size_t)l * EDGE_CH * HIDDEN, be + (size_t)l * HIDDEN, agg);
        mlp_kernel<<<N_NODES / 8, 256, 0, stream>>>(
            agg,
            W1 + (size_t)l * HIDDEN * HIDDEN, b1 + (size_t)l * HIDDEN,
            W2 + (size_t)l * HIDDEN * HIDDEN, b2 + (size_t)l * HIDDEN,
            x, agg, (l < NUM_LAYERS - 1) ? 1 : 0);
    }

    batch_out_kernel<<<(N_NODES + 255) / 256, 256, 0, stream>>>(bv, x + (size_t)N_NODES * HIDDEN);
}

// Round 2
// 1646.147 us; speedup vs baseline: 2.5860x; 2.5860x over previous
//
#include <hip/hip_runtime.h>
#include <math.h>

#define N_NODES 100000
#define N_EDGES 600000
#define HIDDEN 128
#define EDGE_CH 4
#define NUM_LAYERS 3

// ---------------- common kernels ----------------

// x = emb[z]; optionally agg = x (atomic fallback path needs agg pre-init).
__global__ void embed_init_kernel(const float* __restrict__ emb,
                                  const int* __restrict__ z,
                                  float* __restrict__ x,
                                  float* __restrict__ agg,
                                  int write_agg) {
    int t = blockIdx.x * blockDim.x + threadIdx.x;   // N_NODES*32 threads exactly
    int node = t >> 5;
    int c4 = t & 31;
    if (node < N_NODES) {
        float4 v = ((const float4*)(emb + (size_t)z[node] * HIDDEN))[c4];
        ((float4*)(x + (size_t)node * HIDDEN))[c4] = v;
        if (write_agg)
            ((float4*)(agg + (size_t)node * HIDDEN))[c4] = v;
    }
}

// x_new = silu(h@W1 + b1)@W2 + b2. 8 nodes per 256-thread block.
__global__ void mlp_kernel(const float* __restrict__ h,
                           const float* __restrict__ W1, const float* __restrict__ b1,
                           const float* __restrict__ W2, const float* __restrict__ b2,
                           float* __restrict__ x, float* __restrict__ agg_out,
                           int write_agg) {
    __shared__ float hs[8 * HIDDEN];
    __shared__ float ts[8 * HIDDEN];
    int row = threadIdx.x >> 5;
    int c4 = threadIdx.x & 31;
    int node0 = blockIdx.x * 8;
    int node = node0 + row;

    ((float4*)hs)[threadIdx.x] = ((const float4*)(h + (size_t)node0 * HIDDEN))[threadIdx.x];
    __syncthreads();

    float4 acc = ((const float4*)b1)[c4];
    const float* hrow = hs + row * HIDDEN;
    #pragma unroll 8
    for (int k = 0; k < HIDDEN; k++) {
        float hk = hrow[k];
        float4 w = ((const float4*)(W1 + (size_t)k * HIDDEN))[c4];
        acc.x += hk * w.x; acc.y += hk * w.y; acc.z += hk * w.z; acc.w += hk * w.w;
    }
    acc.x = acc.x / (1.f + __expf(-acc.x));
    acc.y = acc.y / (1.f + __expf(-acc.y));
    acc.z = acc.z / (1.f + __expf(-acc.z));
    acc.w = acc.w / (1.f + __expf(-acc.w));
    ((float4*)(ts + row * HIDDEN))[c4] = acc;
    __syncthreads();

    float4 o = ((const float4*)b2)[c4];
    const float* trow = ts + row * HIDDEN;
    #pragma unroll 8
    for (int k = 0; k < HIDDEN; k++) {
        float tk = trow[k];
        float4 w = ((const float4*)(W2 + (size_t)k * HIDDEN))[c4];
        o.x += tk * w.x; o.y += tk * w.y; o.z += tk * w.z; o.w += tk * w.w;
    }
    ((float4*)(x + (size_t)node * HIDDEN))[c4] = o;
    if (write_agg)
        ((float4*)(agg_out + (size_t)node * HIDDEN))[c4] = o;
}

__global__ void batch_out_kernel(const int* __restrict__ bv, float* __restrict__ out) {
    int i = blockIdx.x * blockDim.x + threadIdx.x;
    if (i < N_NODES) out[i] = (float)bv[i];
}

// ---------------- CSR build (fast path) ----------------

__global__ void zero_kernel(int* __restrict__ p, int n) {
    int i = blockIdx.x * blockDim.x + threadIdx.x;
    if (i < n) p[i] = 0;
}

__global__ void hist_kernel(const int* __restrict__ dst, int* __restrict__ cnt) {
    int e = blockIdx.x * blockDim.x + threadIdx.x;
    if (e < N_EDGES) atomicAdd(&cnt[dst[e]], 1);
}

// In-place exclusive scan of cnt[N_NODES]. Single block of 1024 threads.
__global__ void scan_kernel(int* __restrict__ cnt) {
    __shared__ int s[1024];
    const int CH = (N_NODES + 1023) / 1024;     // 98
    int t = threadIdx.x;
    int lo = t * CH;
    int hi = lo + CH; if (hi > N_NODES) hi = N_NODES;
    int sum = 0;
    for (int i = lo; i < hi; i++) sum += cnt[i];
    s[t] = sum;
    __syncthreads();
    // inclusive Hillis-Steele scan of s[0..1023]
    for (int off = 1; off < 1024; off <<= 1) {
        int v = (t >= off) ? s[t - off] : 0;
        __syncthreads();
        s[t] += v;
        __syncthreads();
    }
    int run = (t > 0) ? s[t - 1] : 0;           // exclusive prefix for this chunk
    for (int i = lo; i < hi; i++) {
        int c = cnt[i];
        cnt[i] = run;
        run += c;
    }
}

// Scatter edge ids into CSR order. Mutates pos: afterwards pos[i] = end offset of node i.
__global__ void scatter_kernel(const int* __restrict__ dst,
                               int* __restrict__ pos,
                               int* __restrict__ eids) {
    int e = blockIdx.x * blockDim.x + threadIdx.x;
    if (e < N_EDGES) {
        int p = atomicAdd(&pos[dst[e]], 1);
        eids[p] = e;
    }
}

// Pull-based aggregation: h[i] = x[i] + sum_{e in CSR(i)} relu(x[src[e]] + e_proj).
// 32 lanes (float4) per node, 8 nodes per 256-thread block.
__global__ void gather_kernel(const float* __restrict__ x,
                              const float* __restrict__ edge_attr,
                              const int* __restrict__ src,
                              const int* __restrict__ pos,    // pos[i] = end[i]; start = pos[i-1]
                              const int* __restrict__ eids,
                              const float* __restrict__ We_l,
                              const float* __restrict__ be_l,
                              float* __restrict__ h) {
    __shared__ float sWe[EDGE_CH * HIDDEN];
    __shared__ float sbe[HIDDEN];
    for (int i = threadIdx.x; i < EDGE_CH * HIDDEN; i += blockDim.x) sWe[i] = We_l[i];
    if (threadIdx.x < HIDDEN) sbe[threadIdx.x] = be_l[threadIdx.x];
    __syncthreads();

    int t = blockIdx.x * blockDim.x + threadIdx.x;
    int node = t >> 5;
    int c4 = t & 31;
    if (node >= N_NODES) return;

    int start = (node == 0) ? 0 : pos[node - 1];
    int end = pos[node];

    float4 w0 = ((const float4*)sWe)[0 * 32 + c4];
    float4 w1 = ((const float4*)sWe)[1 * 32 + c4];
    float4 w2 = ((const float4*)sWe)[2 * 32 + c4];
    float4 w3 = ((const float4*)sWe)[3 * 32 + c4];
    float4 bb = ((const float4*)sbe)[c4];

    float4 acc = make_float4(0.f, 0.f, 0.f, 0.f);
    for (int j = start; j < end; j++) {
        int e = eids[j];
        int s = src[e];
        float4 ea = ((const float4*)edge_attr)[e];
        float4 xv = ((const float4*)(x + (size_t)s * HIDDEN))[c4];
        float m0 = xv.x + ea.x * w0.x + ea.y * w1.x + ea.z * w2.x + ea.w * w3.x + bb.x;
        float m1 = xv.y + ea.x * w0.y + ea.y * w1.y + ea.z * w2.y + ea.w * w3.y + bb.y;
        float m2 = xv.z + ea.x * w0.z + ea.y * w1.z + ea.z * w2.z + ea.w * w3.z + bb.z;
        float m3 = xv.w + ea.x * w0.w + ea.y * w1.w + ea.z * w2.w + ea.w * w3.w + bb.w;
        acc.x += fmaxf(m0, 0.f);
        acc.y += fmaxf(m1, 0.f);
        acc.z += fmaxf(m2, 0.f);
        acc.w += fmaxf(m3, 0.f);
    }
    float4 xi = ((const float4*)(x + (size_t)node * HIDDEN))[c4];
    acc.x += xi.x; acc.y += xi.y; acc.z += xi.z; acc.w += xi.w;
    ((float4*)(h + (size_t)node * HIDDEN))[c4] = acc;
}

// ---------------- atomic fallback (round-1 proven path) ----------------

__global__ void edge_kernel(const float* __restrict__ x,
                            const float* __restrict__ edge_attr,
                            const int* __restrict__ src,
                            const int* __restrict__ dst,
                            const float* __restrict__ We_l,
                            const float* __restrict__ be_l,
                            float* __restrict__ agg) {
    __shared__ float sWe[EDGE_CH * HIDDEN];
    __shared__ float sbe[HIDDEN];
    for (int i = threadIdx.x; i < EDGE_CH * HIDDEN; i += blockDim.x) sWe[i] = We_l[i];
    if (threadIdx.x < HIDDEN) sbe[threadIdx.x] = be_l[threadIdx.x];
    __syncthreads();

    int t = blockIdx.x * blockDim.x + threadIdx.x;
    int e = t >> 5;
    if (e >= N_EDGES) return;
    int c4 = t & 31;

    int s = src[e];
    int d = dst[e];
    float4 ea = ((const float4*)edge_attr)[e];
    float4 w0 = ((const float4*)sWe)[0 * 32 + c4];
    float4 w1 = ((const float4*)sWe)[1 * 32 + c4];
    float4 w2 = ((const float4*)sWe)[2 * 32 + c4];
    float4 w3 = ((const float4*)sWe)[3 * 32 + c4];
    float4 bb = ((const float4*)sbe)[c4];
    float4 xv = ((const float4*)(x + (size_t)s * HIDDEN))[c4];

    float m0 = xv.x + ea.x * w0.x + ea.y * w1.x + ea.z * w2.x + ea.w * w3.x + bb.x;
    float m1 = xv.y + ea.x * w0.y + ea.y * w1.y + ea.z * w2.y + ea.w * w3.y + bb.y;
    float m2 = xv.z + ea.x * w0.z + ea.y * w1.z + ea.z * w2.z + ea.w * w3.z + bb.z;
    float m3 = xv.w + ea.x * w0.w + ea.y * w1.w + ea.z * w2.w + ea.w * w3.w + bb.w;

    float* ap = agg + (size_t)d * HIDDEN + c4 * 4;
    atomicAdd(ap + 0, fmaxf(m0, 0.f));
    atomicAdd(ap + 1, fmaxf(m1, 0.f));
    atomicAdd(ap + 2, fmaxf(m2, 0.f));
    atomicAdd(ap + 3, fmaxf(m3, 0.f));
}

// ---------------- host ----------------

extern "C" void kernel_launch(void* const* d_in, const int* in_sizes, int n_in,
                              void* d_out, int out_size, void* d_ws, size_t ws_size,
                              hipStream_t stream) {
    const float* emb       = (const float*)d_in[0];
    const float* We        = (const float*)d_in[1];
    const float* be        = (const float*)d_in[2];
    const float* W1        = (const float*)d_in[3];
    const float* b1        = (const float*)d_in[4];
    const float* W2        = (const float*)d_in[5];
    const float* b2        = (const float*)d_in[6];
    const float* edge_attr = (const float*)d_in[7];
    const int*   z         = (const int*)d_in[8];
    const int*   ei        = (const int*)d_in[9];
    const int*   bv        = (const int*)d_in[10];

    float* x   = (float*)d_out;                 // N_NODES*HIDDEN
    float* agg = (float*)d_ws;                  // N_NODES*HIDDEN (h buffer)
    const int* src = ei;
    const int* dst = ei + N_EDGES;

    const size_t AGG_BYTES = (size_t)N_NODES * HIDDEN * sizeof(float);   // 51.2 MB
    const size_t POS_BYTES = (size_t)N_NODES * sizeof(int);              // 0.4 MB
    const size_t EID_BYTES = (size_t)N_EDGES * sizeof(int);              // 2.4 MB
    const bool fast = (ws_size >= AGG_BYTES + POS_BYTES + EID_BYTES);

    if (fast) {
        int*  pos  = (int*)((char*)d_ws + AGG_BYTES);
        int*  eids = (int*)((char*)d_ws + AGG_BYTES + POS_BYTES);

        embed_init_kernel<<<(N_NODES * 32) / 256, 256, 0, stream>>>(emb, z, x, agg, 0);

        zero_kernel<<<(N_NODES + 255) / 256, 256, 0, stream>>>(pos, N_NODES);
        hist_kernel<<<(N_EDGES + 255) / 256, 256, 0, stream>>>(dst, pos);
        scan_kernel<<<1, 1024, 0, stream>>>(pos);
        scatter_kernel<<<(N_EDGES + 255) / 256, 256, 0, stream>>>(dst, pos, eids);

        for (int l = 0; l < NUM_LAYERS; l++) {
            gather_kernel<<<(N_NODES * 32 + 255) / 256, 256, 0, stream>>>(
                x, edge_attr, src, pos, eids,
                We + (size_t)l * EDGE_CH * HIDDEN, be + (size_t)l * HIDDEN, agg);
            mlp_kernel<<<N_NODES / 8, 256, 0, stream>>>(
                agg,
                W1 + (size_t)l * HIDDEN * HIDDEN, b1 + (size_t)l * HIDDEN,
                W2 + (size_t)l * HIDDEN * HIDDEN, b2 + (size_t)l * HIDDEN,
                x, agg, 0);
        }
    } else {
        // fallback: atomic aggregation (round-1 path)
        embed_init_kernel<<<(N_NODES * 32) / 256, 256, 0, stream>>>(emb, z, x, agg, 1);
        for (int l = 0; l < NUM_LAYERS; l++) {
            edge_kernel<<<(N_EDGES * 32) / 256, 256, 0, stream>>>(
                x, edge_attr, src, dst,
                We + (size_t)l * EDGE_CH * HIDDEN, be + (size_t)l * HIDDEN, agg);
            mlp_kernel<<<N_NODES / 8, 256, 0, stream>>>(
                agg,
                W1 + (size_t)l * HIDDEN * HIDDEN, b1 + (size_t)l * HIDDEN,
                W2 + (size_t)l * HIDDEN * HIDDEN, b2 + (size_t)l * HIDDEN,
                x, agg, (l < NUM_LAYERS - 1) ? 1 : 0);
        }
    }

    batch_out_kernel<<<(N_NODES + 255) / 256, 256, 0, stream>>>(bv, x + (size_t)N_NODES * HIDDEN);
}

// Round 3
// 967.880 us; speedup vs baseline: 4.3982x; 1.7008x over previous
//
#include <hip/hip_runtime.h>
#include <math.h>

#define N_NODES 100000
#define N_EDGES 600000
#define HIDDEN 128
#define EDGE_CH 4
#define NUM_LAYERS 3
#define MLP_ROWS 64   // nodes per block in mlp_kernel

// ---------------- common kernels ----------------

__global__ void embed_init_kernel(const float* __restrict__ emb,
                                  const int* __restrict__ z,
                                  float* __restrict__ x,
                                  float* __restrict__ agg,
                                  int write_agg) {
    int t = blockIdx.x * blockDim.x + threadIdx.x;
    int node = t >> 5;
    int c4 = t & 31;
    if (node < N_NODES) {
        float4 v = ((const float4*)(emb + (size_t)z[node] * HIDDEN))[c4];
        ((float4*)(x + (size_t)node * HIDDEN))[c4] = v;
        if (write_agg)
            ((float4*)(agg + (size_t)node * HIDDEN))[c4] = v;
    }
}

// x_new = silu(h@W1 + b1)@W2 + b2.
// 64 nodes/block, 256 threads = 8 row-groups x 32 col-lanes; each thread does
// 8 rows x 4 cols (each W float4 load feeds 32 FLOPs -> L1 traffic /4 vs naive).
__global__ void mlp_kernel(const float* __restrict__ h,
                           const float* __restrict__ W1, const float* __restrict__ b1,
                           const float* __restrict__ W2, const float* __restrict__ b2,
                           float* __restrict__ x) {
    __shared__ float hs[MLP_ROWS * HIDDEN];   // 32 KB, reused for silu intermediate
    int rg = threadIdx.x >> 5;                // row group 0..7
    int c4 = threadIdx.x & 31;                // output float4 column 0..31
    int node0 = blockIdx.x * MLP_ROWS;

    // stage 64 h rows (2048 float4, 8 per thread), guard tail block
    for (int i = threadIdx.x; i < MLP_ROWS * 32; i += 256) {
        int node = node0 + (i >> 5);
        float4 v = (node < N_NODES)
                 ? ((const float4*)(h + (size_t)node * HIDDEN))[i & 31]
                 : make_float4(0.f, 0.f, 0.f, 0.f);
        ((float4*)hs)[i] = v;
    }
    __syncthreads();

    float4 acc[8];
    {
        float4 bv = ((const float4*)b1)[c4];
        #pragma unroll
        for (int r = 0; r < 8; r++) acc[r] = bv;
    }
    const float* hbase = hs + rg * 8 * HIDDEN;

    for (int k4 = 0; k4 < HIDDEN; k4 += 4) {
        float4 w0 = ((const float4*)(W1 + (size_t)(k4 + 0) * HIDDEN))[c4];
        float4 w1 = ((const float4*)(W1 + (size_t)(k4 + 1) * HIDDEN))[c4];
        float4 w2 = ((const float4*)(W1 + (size_t)(k4 + 2) * HIDDEN))[c4];
        float4 w3 = ((const float4*)(W1 + (size_t)(k4 + 3) * HIDDEN))[c4];
        #pragma unroll
        for (int r = 0; r < 8; r++) {
            float4 hv = *(const float4*)(hbase + r * HIDDEN + k4);
            acc[r].x += hv.x*w0.x + hv.y*w1.x + hv.z*w2.x + hv.w*w3.x;
            acc[r].y += hv.x*w0.y + hv.y*w1.y + hv.z*w2.y + hv.w*w3.y;
            acc[r].z += hv.x*w0.z + hv.y*w1.z + hv.z*w2.z + hv.w*w3.z;
            acc[r].w += hv.x*w0.w + hv.y*w1.w + hv.z*w2.w + hv.w*w3.w;
        }
    }

    __syncthreads();   // all reads of hs done before overwrite
    #pragma unroll
    for (int r = 0; r < 8; r++) {
        float4 a = acc[r];
        a.x = a.x / (1.f + __expf(-a.x));
        a.y = a.y / (1.f + __expf(-a.y));
        a.z = a.z / (1.f + __expf(-a.z));
        a.w = a.w / (1.f + __expf(-a.w));
        *(float4*)(hs + (rg * 8 + r) * HIDDEN + c4 * 4) = a;
    }
    __syncthreads();

    {
        float4 bv = ((const float4*)b2)[c4];
        #pragma unroll
        for (int r = 0; r < 8; r++) acc[r] = bv;
    }
    for (int k4 = 0; k4 < HIDDEN; k4 += 4) {
        float4 w0 = ((const float4*)(W2 + (size_t)(k4 + 0) * HIDDEN))[c4];
        float4 w1 = ((const float4*)(W2 + (size_t)(k4 + 1) * HIDDEN))[c4];
        float4 w2 = ((const float4*)(W2 + (size_t)(k4 + 2) * HIDDEN))[c4];
        float4 w3 = ((const float4*)(W2 + (size_t)(k4 + 3) * HIDDEN))[c4];
        #pragma unroll
        for (int r = 0; r < 8; r++) {
            float4 hv = *(const float4*)(hbase + r * HIDDEN + k4);
            acc[r].x += hv.x*w0.x + hv.y*w1.x + hv.z*w2.x + hv.w*w3.x;
            acc[r].y += hv.x*w0.y + hv.y*w1.y + hv.z*w2.y + hv.w*w3.y;
            acc[r].z += hv.x*w0.z + hv.y*w1.z + hv.z*w2.z + hv.w*w3.z;
            acc[r].w += hv.x*w0.w + hv.y*w1.w + hv.z*w2.w + hv.w*w3.w;
        }
    }

    #pragma unroll
    for (int r = 0; r < 8; r++) {
        int node = node0 + rg * 8 + r;
        if (node < N_NODES)
            ((float4*)(x + (size_t)node * HIDDEN))[c4] = acc[r];
    }
}

__global__ void batch_out_kernel(const int* __restrict__ bv, float* __restrict__ out) {
    int i = blockIdx.x * blockDim.x + threadIdx.x;
    if (i < N_NODES) out[i] = (float)bv[i];
}

// ---------------- CSR build ----------------

__global__ void zero_kernel(int* __restrict__ p, int n) {
    int i = blockIdx.x * blockDim.x + threadIdx.x;
    if (i < n) p[i] = 0;
}

__global__ void hist_kernel(const int* __restrict__ dst, int* __restrict__ cnt) {
    int e = blockIdx.x * blockDim.x + threadIdx.x;
    if (e < N_EDGES) atomicAdd(&cnt[dst[e]], 1);
}

__global__ void scan_kernel(int* __restrict__ cnt) {
    __shared__ int s[1024];
    const int CH = (N_NODES + 1023) / 1024;
    int t = threadIdx.x;
    int lo = t * CH;
    int hi = lo + CH; if (hi > N_NODES) hi = N_NODES;
    int sum = 0;
    for (int i = lo; i < hi; i++) sum += cnt[i];
    s[t] = sum;
    __syncthreads();
    for (int off = 1; off < 1024; off <<= 1) {
        int v = (t >= off) ? s[t - off] : 0;
        __syncthreads();
        s[t] += v;
        __syncthreads();
    }
    int run = (t > 0) ? s[t - 1] : 0;
    for (int i = lo; i < hi; i++) {
        int c = cnt[i];
        cnt[i] = run;
        run += c;
    }
}

// Level A: scatter src + edge_attr directly into CSR order (no eids indirection).
__global__ void scatter2_kernel(const int* __restrict__ dst,
                                const int* __restrict__ src,
                                const float* __restrict__ edge_attr,
                                int* __restrict__ pos,
                                int* __restrict__ ssrc,
                                float4* __restrict__ sea) {
    int e = blockIdx.x * blockDim.x + threadIdx.x;
    if (e < N_EDGES) {
        int p = atomicAdd(&pos[dst[e]], 1);
        ssrc[p] = src[e];
        sea[p] = ((const float4*)edge_attr)[e];
    }
}

// Level A gather: sequential src/ea reads + prefetch; only x[src] is random.
__global__ void gather2_kernel(const float* __restrict__ x,
                               const int* __restrict__ ssrc,
                               const float4* __restrict__ sea,
                               const int* __restrict__ pos,   // pos[i]=end; start=pos[i-1]
                               const float* __restrict__ We_l,
                               const float* __restrict__ be_l,
                               float* __restrict__ h) {
    __shared__ float sWe[EDGE_CH * HIDDEN];
    __shared__ float sbe[HIDDEN];
    for (int i = threadIdx.x; i < EDGE_CH * HIDDEN; i += blockDim.x) sWe[i] = We_l[i];
    if (threadIdx.x < HIDDEN) sbe[threadIdx.x] = be_l[threadIdx.x];
    __syncthreads();

    int t = blockIdx.x * blockDim.x + threadIdx.x;
    int node = t >> 5;
    int c4 = t & 31;
    if (node >= N_NODES) return;

    int start = (node == 0) ? 0 : pos[node - 1];
    int end = pos[node];

    float4 w0 = ((const float4*)sWe)[0 * 32 + c4];
    float4 w1 = ((const float4*)sWe)[1 * 32 + c4];
    float4 w2 = ((const float4*)sWe)[2 * 32 + c4];
    float4 w3 = ((const float4*)sWe)[3 * 32 + c4];
    float4 bb = ((const float4*)sbe)[c4];

    float4 acc = make_float4(0.f, 0.f, 0.f, 0.f);
    int j = start;
    if (j < end) {
        int s0 = ssrc[j];
        float4 ea0 = sea[j];
        for (; j + 1 < end; j++) {
            int s1 = ssrc[j + 1];          // prefetch next while x-gather in flight
            float4 ea1 = sea[j + 1];
            float4 xv = ((const float4*)(x + (size_t)s0 * HIDDEN))[c4];
            float m0 = xv.x + ea0.x*w0.x + ea0.y*w1.x + ea0.z*w2.x + ea0.w*w3.x + bb.x;
            float m1 = xv.y + ea0.x*w0.y + ea0.y*w1.y + ea0.z*w2.y + ea0.w*w3.y + bb.y;
            float m2 = xv.z + ea0.x*w0.z + ea0.y*w1.z + ea0.z*w2.z + ea0.w*w3.z + bb.z;
            float m3 = xv.w + ea0.x*w0.w + ea0.y*w1.w + ea0.z*w2.w + ea0.w*w3.w + bb.w;
            acc.x += fmaxf(m0, 0.f); acc.y += fmaxf(m1, 0.f);
            acc.z += fmaxf(m2, 0.f); acc.w += fmaxf(m3, 0.f);
            s0 = s1; ea0 = ea1;
        }
        float4 xv = ((const float4*)(x + (size_t)s0 * HIDDEN))[c4];
        float m0 = xv.x + ea0.x*w0.x + ea0.y*w1.x + ea0.z*w2.x + ea0.w*w3.x + bb.x;
        float m1 = xv.y + ea0.x*w0.y + ea0.y*w1.y + ea0.z*w2.y + ea0.w*w3.y + bb.y;
        float m2 = xv.z + ea0.x*w0.z + ea0.y*w1.z + ea0.z*w2.z + ea0.w*w3.z + bb.z;
        float m3 = xv.w + ea0.x*w0.w + ea0.y*w1.w + ea0.z*w2.w + ea0.w*w3.w + bb.w;
        acc.x += fmaxf(m0, 0.f); acc.y += fmaxf(m1, 0.f);
        acc.z += fmaxf(m2, 0.f); acc.w += fmaxf(m3, 0.f);
    }
    float4 xi = ((const float4*)(x + (size_t)node * HIDDEN))[c4];
    acc.x += xi.x; acc.y += xi.y; acc.z += xi.z; acc.w += xi.w;
    ((float4*)(h + (size_t)node * HIDDEN))[c4] = acc;
}

// ---------------- Level B (round-2 path) ----------------

__global__ void scatter_kernel(const int* __restrict__ dst,
                               int* __restrict__ pos,
                               int* __restrict__ eids) {
    int e = blockIdx.x * blockDim.x + threadIdx.x;
    if (e < N_EDGES) {
        int p = atomicAdd(&pos[dst[e]], 1);
        eids[p] = e;
    }
}

__global__ void gather_kernel(const float* __restrict__ x,
                              const float* __restrict__ edge_attr,
                              const int* __restrict__ src,
                              const int* __restrict__ pos,
                              const int* __restrict__ eids,
                              const float* __restrict__ We_l,
                              const float* __restrict__ be_l,
                              float* __restrict__ h) {
    __shared__ float sWe[EDGE_CH * HIDDEN];
    __shared__ float sbe[HIDDEN];
    for (int i = threadIdx.x; i < EDGE_CH * HIDDEN; i += blockDim.x) sWe[i] = We_l[i];
    if (threadIdx.x < HIDDEN) sbe[threadIdx.x] = be_l[threadIdx.x];
    __syncthreads();

    int t = blockIdx.x * blockDim.x + threadIdx.x;
    int node = t >> 5;
    int c4 = t & 31;
    if (node >= N_NODES) return;

    int start = (node == 0) ? 0 : pos[node - 1];
    int end = pos[node];

    float4 w0 = ((const float4*)sWe)[0 * 32 + c4];
    float4 w1 = ((const float4*)sWe)[1 * 32 + c4];
    float4 w2 = ((const float4*)sWe)[2 * 32 + c4];
    float4 w3 = ((const float4*)sWe)[3 * 32 + c4];
    float4 bb = ((const float4*)sbe)[c4];

    float4 acc = make_float4(0.f, 0.f, 0.f, 0.f);
    for (int j = start; j < end; j++) {
        int e = eids[j];
        int s = src[e];
        float4 ea = ((const float4*)edge_attr)[e];
        float4 xv = ((const float4*)(x + (size_t)s * HIDDEN))[c4];
        float m0 = xv.x + ea.x*w0.x + ea.y*w1.x + ea.z*w2.x + ea.w*w3.x + bb.x;
        float m1 = xv.y + ea.x*w0.y + ea.y*w1.y + ea.z*w2.y + ea.w*w3.y + bb.y;
        float m2 = xv.z + ea.x*w0.z + ea.y*w1.z + ea.z*w2.z + ea.w*w3.z + bb.z;
        float m3 = xv.w + ea.x*w0.w + ea.y*w1.w + ea.z*w2.w + ea.w*w3.w + bb.w;
        acc.x += fmaxf(m0, 0.f); acc.y += fmaxf(m1, 0.f);
        acc.z += fmaxf(m2, 0.f); acc.w += fmaxf(m3, 0.f);
    }
    float4 xi = ((const float4*)(x + (size_t)node * HIDDEN))[c4];
    acc.x += xi.x; acc.y += xi.y; acc.z += xi.z; acc.w += xi.w;
    ((float4*)(h + (size_t)node * HIDDEN))[c4] = acc;
}

// ---------------- Level C fallback: atomics ----------------

__global__ void edge_kernel(const float* __restrict__ x,
                            const float* __restrict__ edge_attr,
                            const int* __restrict__ src,
                            const int* __restrict__ dst,
                            const float* __restrict__ We_l,
                            const float* __restrict__ be_l,
                            float* __restrict__ agg) {
    __shared__ float sWe[EDGE_CH * HIDDEN];
    __shared__ float sbe[HIDDEN];
    for (int i = threadIdx.x; i < EDGE_CH * HIDDEN; i += blockDim.x) sWe[i] = We_l[i];
    if (threadIdx.x < HIDDEN) sbe[threadIdx.x] = be_l[threadIdx.x];
    __syncthreads();

    int t = blockIdx.x * blockDim.x + threadIdx.x;
    int e = t >> 5;
    if (e >= N_EDGES) return;
    int c4 = t & 31;

    int s = src[e];
    int d = dst[e];
    float4 ea = ((const float4*)edge_attr)[e];
    float4 w0 = ((const float4*)sWe)[0 * 32 + c4];
    float4 w1 = ((const float4*)sWe)[1 * 32 + c4];
    float4 w2 = ((const float4*)sWe)[2 * 32 + c4];
    float4 w3 = ((const float4*)sWe)[3 * 32 + c4];
    float4 bb = ((const float4*)sbe)[c4];
    float4 xv = ((const float4*)(x + (size_t)s * HIDDEN))[c4];

    float m0 = xv.x + ea.x*w0.x + ea.y*w1.x + ea.z*w2.x + ea.w*w3.x + bb.x;
    float m1 = xv.y + ea.x*w0.y + ea.y*w1.y + ea.z*w2.y + ea.w*w3.y + bb.y;
    float m2 = xv.z + ea.x*w0.z + ea.y*w1.z + ea.z*w2.z + ea.w*w3.z + bb.z;
    float m3 = xv.w + ea.x*w0.w + ea.y*w1.w + ea.z*w2.w + ea.w*w3.w + bb.w;

    float* ap = agg + (size_t)d * HIDDEN + c4 * 4;
    atomicAdd(ap + 0, fmaxf(m0, 0.f));
    atomicAdd(ap + 1, fmaxf(m1, 0.f));
    atomicAdd(ap + 2, fmaxf(m2, 0.f));
    atomicAdd(ap + 3, fmaxf(m3, 0.f));
}

// ---------------- host ----------------

extern "C" void kernel_launch(void* const* d_in, const int* in_sizes, int n_in,
                              void* d_out, int out_size, void* d_ws, size_t ws_size,
                              hipStream_t stream) {
    const float* emb       = (const float*)d_in[0];
    const float* We        = (const float*)d_in[1];
    const float* be        = (const float*)d_in[2];
    const float* W1        = (const float*)d_in[3];
    const float* b1        = (const float*)d_in[4];
    const float* W2        = (const float*)d_in[5];
    const float* b2        = (const float*)d_in[6];
    const float* edge_attr = (const float*)d_in[7];
    const int*   z         = (const int*)d_in[8];
    const int*   ei        = (const int*)d_in[9];
    const int*   bv        = (const int*)d_in[10];

    float* x   = (float*)d_out;
    float* agg = (float*)d_ws;
    const int* src = ei;
    const int* dst = ei + N_EDGES;

    const size_t AGG_BYTES = (size_t)N_NODES * HIDDEN * sizeof(float);   // 51.2 MB
    const size_t POS_BYTES = (size_t)N_NODES * sizeof(int);              // 0.4 MB
    const size_t SRC_BYTES = (size_t)N_EDGES * sizeof(int);              // 2.4 MB
    const size_t EA_BYTES  = (size_t)N_EDGES * 4 * sizeof(float);        // 9.6 MB

    const int MLP_GRID = (N_NODES + MLP_ROWS - 1) / MLP_ROWS;

    if (ws_size >= AGG_BYTES + POS_BYTES + SRC_BYTES + EA_BYTES) {
        // Level A: fully de-indirected CSR
        int*    pos  = (int*)((char*)d_ws + AGG_BYTES);
        int*    ssrc = (int*)((char*)d_ws + AGG_BYTES + POS_BYTES);
        float4* sea  = (float4*)((char*)d_ws + AGG_BYTES + POS_BYTES + SRC_BYTES);

        embed_init_kernel<<<(N_NODES * 32) / 256, 256, 0, stream>>>(emb, z, x, agg, 0);
        zero_kernel<<<(N_NODES + 255) / 256, 256, 0, stream>>>(pos, N_NODES);
        hist_kernel<<<(N_EDGES + 255) / 256, 256, 0, stream>>>(dst, pos);
        scan_kernel<<<1, 1024, 0, stream>>>(pos);
        scatter2_kernel<<<(N_EDGES + 255) / 256, 256, 0, stream>>>(dst, src, edge_attr, pos, ssrc, sea);

        for (int l = 0; l < NUM_LAYERS; l++) {
            gather2_kernel<<<(N_NODES * 32 + 255) / 256, 256, 0, stream>>>(
                x, ssrc, sea, pos,
                We + (size_t)l * EDGE_CH * HIDDEN, be + (size_t)l * HIDDEN, agg);
            mlp_kernel<<<MLP_GRID, 256, 0, stream>>>(
                agg,
                W1 + (size_t)l * HIDDEN * HIDDEN, b1 + (size_t)l * HIDDEN,
                W2 + (size_t)l * HIDDEN * HIDDEN, b2 + (size_t)l * HIDDEN, x);
        }
    } else if (ws_size >= AGG_BYTES + POS_BYTES + SRC_BYTES) {
        // Level B: eids CSR (round-2 path)
        int* pos  = (int*)((char*)d_ws + AGG_BYTES);
        int* eids = (int*)((char*)d_ws + AGG_BYTES + POS_BYTES);

        embed_init_kernel<<<(N_NODES * 32) / 256, 256, 0, stream>>>(emb, z, x, agg, 0);
        zero_kernel<<<(N_NODES + 255) / 256, 256, 0, stream>>>(pos, N_NODES);
        hist_kernel<<<(N_EDGES + 255) / 256, 256, 0, stream>>>(dst, pos);
        scan_kernel<<<1, 1024, 0, stream>>>(pos);
        scatter_kernel<<<(N_EDGES + 255) / 256, 256, 0, stream>>>(dst, pos, eids);

        for (int l = 0; l < NUM_LAYERS; l++) {
            gather_kernel<<<(N_NODES * 32 + 255) / 256, 256, 0, stream>>>(
                x, edge_attr, src, pos, eids,
                We + (size_t)l * EDGE_CH * HIDDEN, be + (size_t)l * HIDDEN, agg);
            mlp_kernel<<<MLP_GRID, 256, 0, stream>>>(
                agg,
                W1 + (size_t)l * HIDDEN * HIDDEN, b1 + (size_t)l * HIDDEN,
                W2 + (size_t)l * HIDDEN * HIDDEN, b2 + (size_t)l * HIDDEN, x);
        }
    } else {
        // Level C: atomic fallback
        embed_init_kernel<<<(N_NODES * 32) / 256, 256, 0, stream>>>(emb, z, x, agg, 1);
        for (int l = 0; l < NUM_LAYERS; l++) {
            edge_kernel<<<(N_EDGES * 32) / 256, 256, 0, stream>>>(
                x, edge_attr, src, dst,
                We + (size_t)l * EDGE_CH * HIDDEN, be + (size_t)l * HIDDEN, agg);
            mlp_kernel<<<MLP_GRID, 256, 0, stream>>>(
                agg,
                W1 + (size_t)l * HIDDEN * HIDDEN, b1 + (size_t)l * HIDDEN,
                W2 + (size_t)l * HIDDEN * HIDDEN, b2 + (size_t)l * HIDDEN, x);
        }
    }

    batch_out_kernel<<<(N_NODES + 255) / 256, 256, 0, stream>>>(bv, x + (size_t)N_NODES * HIDDEN);
}

// Round 4
// 760.895 us; speedup vs baseline: 5.5946x; 1.2720x over previous
//
#include <hip/hip_runtime.h>
#include <math.h>

#define N_NODES 100000
#define N_EDGES 600000
#define HIDDEN 128
#define EDGE_CH 4
#define NUM_LAYERS 3
#define MLP_ROWS 64   // nodes per block in mlp_kernel

#define SCAN_BLOCK 256
#define SCAN_GRID ((N_NODES + SCAN_BLOCK - 1) / SCAN_BLOCK)   // 391

// ---------------- common kernels ----------------

__global__ void embed_init_kernel(const float* __restrict__ emb,
                                  const int* __restrict__ z,
                                  float* __restrict__ x,
                                  float* __restrict__ agg,
                                  int write_agg) {
    int t = blockIdx.x * blockDim.x + threadIdx.x;
    int node = t >> 5;
    int c4 = t & 31;
    if (node < N_NODES) {
        float4 v = ((const float4*)(emb + (size_t)z[node] * HIDDEN))[c4];
        ((float4*)(x + (size_t)node * HIDDEN))[c4] = v;
        if (write_agg)
            ((float4*)(agg + (size_t)node * HIDDEN))[c4] = v;
    }
}

// x_new = silu(h@W1 + b1)@W2 + b2.
// 64 nodes/block, 256 threads = 8 row-groups x 32 col-lanes; each thread does
// 8 rows x 4 cols (each W float4 load feeds 32 FLOPs).
__global__ void mlp_kernel(const float* __restrict__ h,
                           const float* __restrict__ W1, const float* __restrict__ b1,
                           const float* __restrict__ W2, const float* __restrict__ b2,
                           float* __restrict__ x) {
    __shared__ float hs[MLP_ROWS * HIDDEN];   // 32 KB, reused for silu intermediate
    int rg = threadIdx.x >> 5;
    int c4 = threadIdx.x & 31;
    int node0 = blockIdx.x * MLP_ROWS;

    for (int i = threadIdx.x; i < MLP_ROWS * 32; i += 256) {
        int node = node0 + (i >> 5);
        float4 v = (node < N_NODES)
                 ? ((const float4*)(h + (size_t)node * HIDDEN))[i & 31]
                 : make_float4(0.f, 0.f, 0.f, 0.f);
        ((float4*)hs)[i] = v;
    }
    __syncthreads();

    float4 acc[8];
    {
        float4 bv = ((const float4*)b1)[c4];
        #pragma unroll
        for (int r = 0; r < 8; r++) acc[r] = bv;
    }
    const float* hbase = hs + rg * 8 * HIDDEN;

    for (int k4 = 0; k4 < HIDDEN; k4 += 4) {
        float4 w0 = ((const float4*)(W1 + (size_t)(k4 + 0) * HIDDEN))[c4];
        float4 w1 = ((const float4*)(W1 + (size_t)(k4 + 1) * HIDDEN))[c4];
        float4 w2 = ((const float4*)(W1 + (size_t)(k4 + 2) * HIDDEN))[c4];
        float4 w3 = ((const float4*)(W1 + (size_t)(k4 + 3) * HIDDEN))[c4];
        #pragma unroll
        for (int r = 0; r < 8; r++) {
            float4 hv = *(const float4*)(hbase + r * HIDDEN + k4);
            acc[r].x += hv.x*w0.x + hv.y*w1.x + hv.z*w2.x + hv.w*w3.x;
            acc[r].y += hv.x*w0.y + hv.y*w1.y + hv.z*w2.y + hv.w*w3.y;
            acc[r].z += hv.x*w0.z + hv.y*w1.z + hv.z*w2.z + hv.w*w3.z;
            acc[r].w += hv.x*w0.w + hv.y*w1.w + hv.z*w2.w + hv.w*w3.w;
        }
    }

    __syncthreads();
    #pragma unroll
    for (int r = 0; r < 8; r++) {
        float4 a = acc[r];
        a.x = a.x / (1.f + __expf(-a.x));
        a.y = a.y / (1.f + __expf(-a.y));
        a.z = a.z / (1.f + __expf(-a.z));
        a.w = a.w / (1.f + __expf(-a.w));
        *(float4*)(hs + (rg * 8 + r) * HIDDEN + c4 * 4) = a;
    }
    __syncthreads();

    {
        float4 bv = ((const float4*)b2)[c4];
        #pragma unroll
        for (int r = 0; r < 8; r++) acc[r] = bv;
    }
    for (int k4 = 0; k4 < HIDDEN; k4 += 4) {
        float4 w0 = ((const float4*)(W2 + (size_t)(k4 + 0) * HIDDEN))[c4];
        float4 w1 = ((const float4*)(W2 + (size_t)(k4 + 1) * HIDDEN))[c4];
        float4 w2 = ((const float4*)(W2 + (size_t)(k4 + 2) * HIDDEN))[c4];
        float4 w3 = ((const float4*)(W2 + (size_t)(k4 + 3) * HIDDEN))[c4];
        #pragma unroll
        for (int r = 0; r < 8; r++) {
            float4 hv = *(const float4*)(hbase + r * HIDDEN + k4);
            acc[r].x += hv.x*w0.x + hv.y*w1.x + hv.z*w2.x + hv.w*w3.x;
            acc[r].y += hv.x*w0.y + hv.y*w1.y + hv.z*w2.y + hv.w*w3.y;
            acc[r].z += hv.x*w0.z + hv.y*w1.z + hv.z*w2.z + hv.w*w3.z;
            acc[r].w += hv.x*w0.w + hv.y*w1.w + hv.z*w2.w + hv.w*w3.w;
        }
    }

    #pragma unroll
    for (int r = 0; r < 8; r++) {
        int node = node0 + rg * 8 + r;
        if (node < N_NODES)
            ((float4*)(x + (size_t)node * HIDDEN))[c4] = acc[r];
    }
}

__global__ void batch_out_kernel(const int* __restrict__ bv, float* __restrict__ out) {
    int i = blockIdx.x * blockDim.x + threadIdx.x;
    if (i < N_NODES) out[i] = (float)bv[i];
}

// ---------------- CSR build ----------------

__global__ void zero_kernel(int* __restrict__ p, int n) {
    int i = blockIdx.x * blockDim.x + threadIdx.x;
    if (i < n) p[i] = 0;
}

__global__ void hist_kernel(const int* __restrict__ dst, int* __restrict__ cnt) {
    int e = blockIdx.x * blockDim.x + threadIdx.x;
    if (e < N_EDGES) atomicAdd(&cnt[dst[e]], 1);
}

// --- parallel 3-phase exclusive scan of cnt[N_NODES] (in place) ---

__global__ void scan_partial_kernel(const int* __restrict__ cnt, int* __restrict__ bsum) {
    __shared__ int s[SCAN_BLOCK];
    int i = blockIdx.x * SCAN_BLOCK + threadIdx.x;
    s[threadIdx.x] = (i < N_NODES) ? cnt[i] : 0;
    __syncthreads();
    for (int off = SCAN_BLOCK / 2; off > 0; off >>= 1) {
        if (threadIdx.x < off) s[threadIdx.x] += s[threadIdx.x + off];
        __syncthreads();
    }
    if (threadIdx.x == 0) bsum[blockIdx.x] = s[0];
}

// exclusive scan of bsum[SCAN_GRID]; 1 block of 512 threads
__global__ void scan_base_kernel(int* __restrict__ bsum) {
    __shared__ int s[512];
    int t = threadIdx.x;
    s[t] = (t < SCAN_GRID) ? bsum[t] : 0;
    __syncthreads();
    for (int off = 1; off < 512; off <<= 1) {
        int v = (t >= off) ? s[t - off] : 0;
        __syncthreads();
        s[t] += v;
        __syncthreads();
    }
    if (t < SCAN_GRID) bsum[t] = (t > 0) ? s[t - 1] : 0;
}

// in-place: pos[i] = bsum[block] + inclusive_scan(block)[i] - cnt[i]
// (each element read & written only by its own block -> cross-block safe)
__global__ void scan_final_kernel(int* __restrict__ cnt, const int* __restrict__ bsum) {
    __shared__ int s[SCAN_BLOCK];
    int i = blockIdx.x * SCAN_BLOCK + threadIdx.x;
    int v = (i < N_NODES) ? cnt[i] : 0;
    s[threadIdx.x] = v;
    __syncthreads();
    for (int off = 1; off < SCAN_BLOCK; off <<= 1) {
        int u = (threadIdx.x >= off) ? s[threadIdx.x - off] : 0;
        __syncthreads();
        s[threadIdx.x] += u;
        __syncthreads();
    }
    if (i < N_NODES) cnt[i] = bsum[blockIdx.x] + s[threadIdx.x] - v;
}

// Level A: scatter src + edge_attr directly into CSR order.
__global__ void scatter2_kernel(const int* __restrict__ dst,
                                const int* __restrict__ src,
                                const float* __restrict__ edge_attr,
                                int* __restrict__ pos,
                                int* __restrict__ ssrc,
                                float4* __restrict__ sea) {
    int e = blockIdx.x * blockDim.x + threadIdx.x;
    if (e < N_EDGES) {
        int p = atomicAdd(&pos[dst[e]], 1);
        ssrc[p] = src[e];
        sea[p] = ((const float4*)edge_attr)[e];
    }
}

// Level A gather: sequential src/ea reads + prefetch; only x[src] is random.
__global__ void gather2_kernel(const float* __restrict__ x,
                               const int* __restrict__ ssrc,
                               const float4* __restrict__ sea,
                               const int* __restrict__ pos,   // pos[i]=end; start=pos[i-1]
                               const float* __restrict__ We_l,
                               const float* __restrict__ be_l,
                               float* __restrict__ h) {
    __shared__ float sWe[EDGE_CH * HIDDEN];
    __shared__ float sbe[HIDDEN];
    for (int i = threadIdx.x; i < EDGE_CH * HIDDEN; i += blockDim.x) sWe[i] = We_l[i];
    if (threadIdx.x < HIDDEN) sbe[threadIdx.x] = be_l[threadIdx.x];
    __syncthreads();

    int t = blockIdx.x * blockDim.x + threadIdx.x;
    int node = t >> 5;
    int c4 = t & 31;
    if (node >= N_NODES) return;

    int start = (node == 0) ? 0 : pos[node - 1];
    int end = pos[node];

    float4 w0 = ((const float4*)sWe)[0 * 32 + c4];
    float4 w1 = ((const float4*)sWe)[1 * 32 + c4];
    float4 w2 = ((const float4*)sWe)[2 * 32 + c4];
    float4 w3 = ((const float4*)sWe)[3 * 32 + c4];
    float4 bb = ((const float4*)sbe)[c4];

    float4 acc = make_float4(0.f, 0.f, 0.f, 0.f);
    int j = start;
    if (j < end) {
        int s0 = ssrc[j];
        float4 ea0 = sea[j];
        for (; j + 1 < end; j++) {
            int s1 = ssrc[j + 1];
            float4 ea1 = sea[j + 1];
            float4 xv = ((const float4*)(x + (size_t)s0 * HIDDEN))[c4];
            float m0 = xv.x + ea0.x*w0.x + ea0.y*w1.x + ea0.z*w2.x + ea0.w*w3.x + bb.x;
            float m1 = xv.y + ea0.x*w0.y + ea0.y*w1.y + ea0.z*w2.y + ea0.w*w3.y + bb.y;
            float m2 = xv.z + ea0.x*w0.z + ea0.y*w1.z + ea0.z*w2.z + ea0.w*w3.z + bb.z;
            float m3 = xv.w + ea0.x*w0.w + ea0.y*w1.w + ea0.z*w2.w + ea0.w*w3.w + bb.w;
            acc.x += fmaxf(m0, 0.f); acc.y += fmaxf(m1, 0.f);
            acc.z += fmaxf(m2, 0.f); acc.w += fmaxf(m3, 0.f);
            s0 = s1; ea0 = ea1;
        }
        float4 xv = ((const float4*)(x + (size_t)s0 * HIDDEN))[c4];
        float m0 = xv.x + ea0.x*w0.x + ea0.y*w1.x + ea0.z*w2.x + ea0.w*w3.x + bb.x;
        float m1 = xv.y + ea0.x*w0.y + ea0.y*w1.y + ea0.z*w2.y + ea0.w*w3.y + bb.y;
        float m2 = xv.z + ea0.x*w0.z + ea0.y*w1.z + ea0.z*w2.z + ea0.w*w3.z + bb.z;
        float m3 = xv.w + ea0.x*w0.w + ea0.y*w1.w + ea0.z*w2.w + ea0.w*w3.w + bb.w;
        acc.x += fmaxf(m0, 0.f); acc.y += fmaxf(m1, 0.f);
        acc.z += fmaxf(m2, 0.f); acc.w += fmaxf(m3, 0.f);
    }
    float4 xi = ((const float4*)(x + (size_t)node * HIDDEN))[c4];
    acc.x += xi.x; acc.y += xi.y; acc.z += xi.z; acc.w += xi.w;
    ((float4*)(h + (size_t)node * HIDDEN))[c4] = acc;
}

// ---------------- Level C fallback: atomics ----------------

__global__ void edge_kernel(const float* __restrict__ x,
                            const float* __restrict__ edge_attr,
                            const int* __restrict__ src,
                            const int* __restrict__ dst,
                            const float* __restrict__ We_l,
                            const float* __restrict__ be_l,
                            float* __restrict__ agg) {
    __shared__ float sWe[EDGE_CH * HIDDEN];
    __shared__ float sbe[HIDDEN];
    for (int i = threadIdx.x; i < EDGE_CH * HIDDEN; i += blockDim.x) sWe[i] = We_l[i];
    if (threadIdx.x < HIDDEN) sbe[threadIdx.x] = be_l[threadIdx.x];
    __syncthreads();

    int t = blockIdx.x * blockDim.x + threadIdx.x;
    int e = t >> 5;
    if (e >= N_EDGES) return;
    int c4 = t & 31;

    int s = src[e];
    int d = dst[e];
    float4 ea = ((const float4*)edge_attr)[e];
    float4 w0 = ((const float4*)sWe)[0 * 32 + c4];
    float4 w1 = ((const float4*)sWe)[1 * 32 + c4];
    float4 w2 = ((const float4*)sWe)[2 * 32 + c4];
    float4 w3 = ((const float4*)sWe)[3 * 32 + c4];
    float4 bb = ((const float4*)sbe)[c4];
    float4 xv = ((const float4*)(x + (size_t)s * HIDDEN))[c4];

    float m0 = xv.x + ea.x*w0.x + ea.y*w1.x + ea.z*w2.x + ea.w*w3.x + bb.x;
    float m1 = xv.y + ea.x*w0.y + ea.y*w1.y + ea.z*w2.y + ea.w*w3.y + bb.y;
    float m2 = xv.z + ea.x*w0.z + ea.y*w1.z + ea.z*w2.z + ea.w*w3.z + bb.z;
    float m3 = xv.w + ea.x*w0.w + ea.y*w1.w + ea.z*w2.w + ea.w*w3.w + bb.w;

    float* ap = agg + (size_t)d * HIDDEN + c4 * 4;
    atomicAdd(ap + 0, fmaxf(m0, 0.f));
    atomicAdd(ap + 1, fmaxf(m1, 0.f));
    atomicAdd(ap + 2, fmaxf(m2, 0.f));
    atomicAdd(ap + 3, fmaxf(m3, 0.f));
}

// ---------------- host ----------------

extern "C" void kernel_launch(void* const* d_in, const int* in_sizes, int n_in,
                              void* d_out, int out_size, void* d_ws, size_t ws_size,
                              hipStream_t stream) {
    const float* emb       = (const float*)d_in[0];
    const float* We        = (const float*)d_in[1];
    const float* be        = (const float*)d_in[2];
    const float* W1        = (const float*)d_in[3];
    const float* b1        = (const float*)d_in[4];
    const float* W2        = (const float*)d_in[5];
    const float* b2        = (const float*)d_in[6];
    const float* edge_attr = (const float*)d_in[7];
    const int*   z         = (const int*)d_in[8];
    const int*   ei        = (const int*)d_in[9];
    const int*   bv        = (const int*)d_in[10];

    float* x   = (float*)d_out;
    float* agg = (float*)d_ws;
    const int* src = ei;
    const int* dst = ei + N_EDGES;

    const size_t AGG_BYTES  = (size_t)N_NODES * HIDDEN * sizeof(float);   // 51.2 MB
    const size_t POS_BYTES  = (size_t)N_NODES * sizeof(int);              // 0.4 MB
    const size_t SRC_BYTES  = (size_t)N_EDGES * sizeof(int);              // 2.4 MB
    const size_t EA_BYTES   = (size_t)N_EDGES * 4 * sizeof(float);        // 9.6 MB
    const size_t BSUM_BYTES = (size_t)SCAN_GRID * sizeof(int);            // ~1.6 KB

    const int MLP_GRID = (N_NODES + MLP_ROWS - 1) / MLP_ROWS;

    if (ws_size >= AGG_BYTES + POS_BYTES + SRC_BYTES + EA_BYTES + BSUM_BYTES) {
        // Level A: fully de-indirected CSR, parallel scan
        int*    pos  = (int*)((char*)d_ws + AGG_BYTES);
        int*    ssrc = (int*)((char*)d_ws + AGG_BYTES + POS_BYTES);
        float4* sea  = (float4*)((char*)d_ws + AGG_BYTES + POS_BYTES + SRC_BYTES);
        int*    bsum = (int*)((char*)d_ws + AGG_BYTES + POS_BYTES + SRC_BYTES + EA_BYTES);

        embed_init_kernel<<<(N_NODES * 32) / 256, 256, 0, stream>>>(emb, z, x, agg, 0);
        zero_kernel<<<(N_NODES + 255) / 256, 256, 0, stream>>>(pos, N_NODES);
        hist_kernel<<<(N_EDGES + 255) / 256, 256, 0, stream>>>(dst, pos);
        scan_partial_kernel<<<SCAN_GRID, SCAN_BLOCK, 0, stream>>>(pos, bsum);
        scan_base_kernel<<<1, 512, 0, stream>>>(bsum);
        scan_final_kernel<<<SCAN_GRID, SCAN_BLOCK, 0, stream>>>(pos, bsum);
        scatter2_kernel<<<(N_EDGES + 255) / 256, 256, 0, stream>>>(dst, src, edge_attr, pos, ssrc, sea);

        for (int l = 0; l < NUM_LAYERS; l++) {
            gather2_kernel<<<(N_NODES * 32 + 255) / 256, 256, 0, stream>>>(
                x, ssrc, sea, pos,
                We + (size_t)l * EDGE_CH * HIDDEN, be + (size_t)l * HIDDEN, agg);
            mlp_kernel<<<MLP_GRID, 256, 0, stream>>>(
                agg,
                W1 + (size_t)l * HIDDEN * HIDDEN, b1 + (size_t)l * HIDDEN,
                W2 + (size_t)l * HIDDEN * HIDDEN, b2 + (size_t)l * HIDDEN, x);
        }
    } else {
        // Level C: atomic fallback
        embed_init_kernel<<<(N_NODES * 32) / 256, 256, 0, stream>>>(emb, z, x, agg, 1);
        for (int l = 0; l < NUM_LAYERS; l++) {
            edge_kernel<<<(N_EDGES * 32) / 256, 256, 0, stream>>>(
                x, edge_attr, src, dst,
                We + (size_t)l * EDGE_CH * HIDDEN, be + (size_t)l * HIDDEN, agg);
            mlp_kernel<<<MLP_GRID, 256, 0, stream>>>(
                agg,
                W1 + (size_t)l * HIDDEN * HIDDEN, b1 + (size_t)l * HIDDEN,
                W2 + (size_t)l * HIDDEN * HIDDEN, b2 + (size_t)l * HIDDEN, x);
        }
    }

    batch_out_kernel<<<(N_NODES + 255) / 256, 256, 0, stream>>>(bv, x + (size_t)N_NODES * HIDDEN);
}

// Round 5
// 693.405 us; speedup vs baseline: 6.1391x; 1.0973x over previous
//
#include <hip/hip_runtime.h>
#include <math.h>

#define N_NODES 100000
#define N_EDGES 600000
#define HIDDEN 128
#define EDGE_CH 4
#define NUM_LAYERS 3
#define MLP_ROWS 64   // nodes per block in fp32 fallback mlp_kernel

#define SCAN_BLOCK 256
#define SCAN_GRID ((N_NODES + SCAN_BLOCK - 1) / SCAN_BLOCK)   // 391

#define HSTR 132      // padded LDS row stride (floats) for MFMA mlp: bank = (4*row + k) % 32

typedef short bf16x8 __attribute__((ext_vector_type(8)));
typedef float f32x4  __attribute__((ext_vector_type(4)));

__device__ inline unsigned short f2bf(float x) {           // RNE fp32 -> bf16 bits
    unsigned u = __float_as_uint(x);
    return (unsigned short)((u + 0x7fff + ((u >> 16) & 1)) >> 16);
}
__device__ inline float bf2f(unsigned short b) { return __uint_as_float(((unsigned)b) << 16); }

// ---------------- common kernels ----------------

__global__ void embed_init_kernel(const float* __restrict__ emb,
                                  const int* __restrict__ z,
                                  float* __restrict__ x,
                                  float* __restrict__ agg,
                                  int write_agg) {
    int t = blockIdx.x * blockDim.x + threadIdx.x;
    int node = t >> 5;
    int c4 = t & 31;
    if (node < N_NODES) {
        float4 v = ((const float4*)(emb + (size_t)z[node] * HIDDEN))[c4];
        ((float4*)(x + (size_t)node * HIDDEN))[c4] = v;
        if (write_agg)
            ((float4*)(agg + (size_t)node * HIDDEN))[c4] = v;
    }
}

// Pre-split W1/W2 (all layers) into transposed bf16 hi/lo: wt[(l*2+mat)*16384 + n*128 + k]
__global__ void wprep_kernel(const float* __restrict__ W1, const float* __restrict__ W2,
                             unsigned short* __restrict__ wt_hi,
                             unsigned short* __restrict__ wt_lo) {
    int idx = blockIdx.x * blockDim.x + threadIdx.x;
    if (idx >= NUM_LAYERS * 2 * HIDDEN * HIDDEN) return;
    int k   = idx & 127;
    int n   = (idx >> 7) & 127;
    int mat = (idx >> 14) & 1;
    int l   = idx >> 15;
    const float* W = mat ? W2 : W1;
    float v = W[(size_t)l * HIDDEN * HIDDEN + (size_t)k * HIDDEN + n];
    unsigned short hi = f2bf(v);
    unsigned short lo = f2bf(v - bf2f(hi));
    wt_hi[idx] = hi;
    wt_lo[idx] = lo;
}

// MFMA MLP: x = silu(h@W1 + b1)@W2 + b2, split-bf16 (3-term) per GEMM.
// 256 threads = 4 waves, 16 nodes/wave, 64 nodes/block.
__global__ __launch_bounds__(256, 4) void mlp_mfma_kernel(
        const float* __restrict__ h,
        const unsigned short* __restrict__ wt1_hi, const unsigned short* __restrict__ wt1_lo,
        const unsigned short* __restrict__ wt2_hi, const unsigned short* __restrict__ wt2_lo,
        const float* __restrict__ b1, const float* __restrict__ b2,
        float* __restrict__ x) {
    __shared__ float sh[4 * 16 * HSTR];      // 33792 B; per-wave private 16xHSTR region
    int wave  = threadIdx.x >> 6;
    int lane  = threadIdx.x & 63;
    int row16 = lane & 15;                   // m (A) / n-within-tile (B,D)
    int quad  = lane >> 4;
    int wnode0 = blockIdx.x * 64 + wave * 16;
    float* myh = sh + wave * 16 * HSTR;

    // stage this wave's 16 h-rows (fp32) into padded LDS
    for (int i = lane; i < 512; i += 64) {
        int r = i >> 5, c4 = i & 31;
        int node = wnode0 + r;
        float4 v = (node < N_NODES) ? ((const float4*)(h + (size_t)node * HIDDEN))[c4]
                                    : make_float4(0.f, 0.f, 0.f, 0.f);
        *(float4*)(myh + r * HSTR + c4 * 4) = v;
    }
    __syncthreads();

    bf16x8 ahi[4], alo[4];
    // A-fragments from h: A[m=lane&15][k=quad*8+j], 4 k-steps of 32
    #pragma unroll
    for (int ks = 0; ks < 4; ks++) {
        const float* p = myh + row16 * HSTR + ks * 32 + quad * 8;
        bf16x8 hi, lo;
        #pragma unroll
        for (int j = 0; j < 8; j++) {
            float v = p[j];
            unsigned short hb = f2bf(v);
            hi[j] = (short)hb;
            lo[j] = (short)f2bf(v - bf2f(hb));
        }
        ahi[ks] = hi; alo[ks] = lo;
    }

    // GEMM1 (+bias, silu) -> t into same per-wave LDS region
    #pragma unroll
    for (int nt = 0; nt < 8; nt++) {
        f32x4 acc = {0.f, 0.f, 0.f, 0.f};
        int n = nt * 16 + row16;
        #pragma unroll
        for (int ks = 0; ks < 4; ks++) {
            bf16x8 bhi = *(const bf16x8*)(wt1_hi + n * HIDDEN + ks * 32 + quad * 8);
            bf16x8 blo = *(const bf16x8*)(wt1_lo + n * HIDDEN + ks * 32 + quad * 8);
            acc = __builtin_amdgcn_mfma_f32_16x16x32_bf16(ahi[ks], bhi, acc, 0, 0, 0);
            acc = __builtin_amdgcn_mfma_f32_16x16x32_bf16(alo[ks], bhi, acc, 0, 0, 0);
            acc = __builtin_amdgcn_mfma_f32_16x16x32_bf16(ahi[ks], blo, acc, 0, 0, 0);
        }
        float bias = b1[n];
        #pragma unroll
        for (int r = 0; r < 4; r++) {         // D: col = lane&15, row = quad*4 + r
            float v = acc[r] + bias;
            v = v / (1.f + __expf(-v));
            myh[(quad * 4 + r) * HSTR + n] = v;
        }
    }
    __syncthreads();

    // A-fragments from t
    #pragma unroll
    for (int ks = 0; ks < 4; ks++) {
        const float* p = myh + row16 * HSTR + ks * 32 + quad * 8;
        bf16x8 hi, lo;
        #pragma unroll
        for (int j = 0; j < 8; j++) {
            float v = p[j];
            unsigned short hb = f2bf(v);
            hi[j] = (short)hb;
            lo[j] = (short)f2bf(v - bf2f(hb));
        }
        ahi[ks] = hi; alo[ks] = lo;
    }

    // GEMM2 (+bias) -> global x
    #pragma unroll
    for (int nt = 0; nt < 8; nt++) {
        f32x4 acc = {0.f, 0.f, 0.f, 0.f};
        int n = nt * 16 + row16;
        #pragma unroll
        for (int ks = 0; ks < 4; ks++) {
            bf16x8 bhi = *(const bf16x8*)(wt2_hi + n * HIDDEN + ks * 32 + quad * 8);
            bf16x8 blo = *(const bf16x8*)(wt2_lo + n * HIDDEN + ks * 32 + quad * 8);
            acc = __builtin_amdgcn_mfma_f32_16x16x32_bf16(ahi[ks], bhi, acc, 0, 0, 0);
            acc = __builtin_amdgcn_mfma_f32_16x16x32_bf16(alo[ks], bhi, acc, 0, 0, 0);
            acc = __builtin_amdgcn_mfma_f32_16x16x32_bf16(ahi[ks], blo, acc, 0, 0, 0);
        }
        float bias = b2[n];
        #pragma unroll
        for (int r = 0; r < 4; r++) {
            int node = wnode0 + quad * 4 + r;
            if (node < N_NODES)
                x[(size_t)node * HIDDEN + n] = acc[r] + bias;
        }
    }
}

// fp32 fallback MLP (round-4 path)
__global__ void mlp_kernel(const float* __restrict__ h,
                           const float* __restrict__ W1, const float* __restrict__ b1,
                           const float* __restrict__ W2, const float* __restrict__ b2,
                           float* __restrict__ x) {
    __shared__ float hs[MLP_ROWS * HIDDEN];
    int rg = threadIdx.x >> 5;
    int c4 = threadIdx.x & 31;
    int node0 = blockIdx.x * MLP_ROWS;

    for (int i = threadIdx.x; i < MLP_ROWS * 32; i += 256) {
        int node = node0 + (i >> 5);
        float4 v = (node < N_NODES)
                 ? ((const float4*)(h + (size_t)node * HIDDEN))[i & 31]
                 : make_float4(0.f, 0.f, 0.f, 0.f);
        ((float4*)hs)[i] = v;
    }
    __syncthreads();

    float4 acc[8];
    {
        float4 bv = ((const float4*)b1)[c4];
        #pragma unroll
        for (int r = 0; r < 8; r++) acc[r] = bv;
    }
    const float* hbase = hs + rg * 8 * HIDDEN;

    for (int k4 = 0; k4 < HIDDEN; k4 += 4) {
        float4 w0 = ((const float4*)(W1 + (size_t)(k4 + 0) * HIDDEN))[c4];
        float4 w1 = ((const float4*)(W1 + (size_t)(k4 + 1) * HIDDEN))[c4];
        float4 w2 = ((const float4*)(W1 + (size_t)(k4 + 2) * HIDDEN))[c4];
        float4 w3 = ((const float4*)(W1 + (size_t)(k4 + 3) * HIDDEN))[c4];
        #pragma unroll
        for (int r = 0; r < 8; r++) {
            float4 hv = *(const float4*)(hbase + r * HIDDEN + k4);
            acc[r].x += hv.x*w0.x + hv.y*w1.x + hv.z*w2.x + hv.w*w3.x;
            acc[r].y += hv.x*w0.y + hv.y*w1.y + hv.z*w2.y + hv.w*w3.y;
            acc[r].z += hv.x*w0.z + hv.y*w1.z + hv.z*w2.z + hv.w*w3.z;
            acc[r].w += hv.x*w0.w + hv.y*w1.w + hv.z*w2.w + hv.w*w3.w;
        }
    }

    __syncthreads();
    #pragma unroll
    for (int r = 0; r < 8; r++) {
        float4 a = acc[r];
        a.x = a.x / (1.f + __expf(-a.x));
        a.y = a.y / (1.f + __expf(-a.y));
        a.z = a.z / (1.f + __expf(-a.z));
        a.w = a.w / (1.f + __expf(-a.w));
        *(float4*)(hs + (rg * 8 + r) * HIDDEN + c4 * 4) = a;
    }
    __syncthreads();

    {
        float4 bv = ((const float4*)b2)[c4];
        #pragma unroll
        for (int r = 0; r < 8; r++) acc[r] = bv;
    }
    for (int k4 = 0; k4 < HIDDEN; k4 += 4) {
        float4 w0 = ((const float4*)(W2 + (size_t)(k4 + 0) * HIDDEN))[c4];
        float4 w1 = ((const float4*)(W2 + (size_t)(k4 + 1) * HIDDEN))[c4];
        float4 w2 = ((const float4*)(W2 + (size_t)(k4 + 2) * HIDDEN))[c4];
        float4 w3 = ((const float4*)(W2 + (size_t)(k4 + 3) * HIDDEN))[c4];
        #pragma unroll
        for (int r = 0; r < 8; r++) {
            float4 hv = *(const float4*)(hbase + r * HIDDEN + k4);
            acc[r].x += hv.x*w0.x + hv.y*w1.x + hv.z*w2.x + hv.w*w3.x;
            acc[r].y += hv.x*w0.y + hv.y*w1.y + hv.z*w2.y + hv.w*w3.y;
            acc[r].z += hv.x*w0.z + hv.y*w1.z + hv.z*w2.z + hv.w*w3.z;
            acc[r].w += hv.x*w0.w + hv.y*w1.w + hv.z*w2.w + hv.w*w3.w;
        }
    }

    #pragma unroll
    for (int r = 0; r < 8; r++) {
        int node = node0 + rg * 8 + r;
        if (node < N_NODES)
            ((float4*)(x + (size_t)node * HIDDEN))[c4] = acc[r];
    }
}

__global__ void batch_out_kernel(const int* __restrict__ bv, float* __restrict__ out) {
    int i = blockIdx.x * blockDim.x + threadIdx.x;
    if (i < N_NODES) out[i] = (float)bv[i];
}

// ---------------- CSR build ----------------

__global__ void zero_kernel(int* __restrict__ p, int n) {
    int i = blockIdx.x * blockDim.x + threadIdx.x;
    if (i < n) p[i] = 0;
}

__global__ void hist_kernel(const int* __restrict__ dst, int* __restrict__ cnt) {
    int e = blockIdx.x * blockDim.x + threadIdx.x;
    if (e < N_EDGES) atomicAdd(&cnt[dst[e]], 1);
}

__global__ void scan_partial_kernel(const int* __restrict__ cnt, int* __restrict__ bsum) {
    __shared__ int s[SCAN_BLOCK];
    int i = blockIdx.x * SCAN_BLOCK + threadIdx.x;
    s[threadIdx.x] = (i < N_NODES) ? cnt[i] : 0;
    __syncthreads();
    for (int off = SCAN_BLOCK / 2; off > 0; off >>= 1) {
        if (threadIdx.x < off) s[threadIdx.x] += s[threadIdx.x + off];
        __syncthreads();
    }
    if (threadIdx.x == 0) bsum[blockIdx.x] = s[0];
}

__global__ void scan_base_kernel(int* __restrict__ bsum) {
    __shared__ int s[512];
    int t = threadIdx.x;
    s[t] = (t < SCAN_GRID) ? bsum[t] : 0;
    __syncthreads();
    for (int off = 1; off < 512; off <<= 1) {
        int v = (t >= off) ? s[t - off] : 0;
        __syncthreads();
        s[t] += v;
        __syncthreads();
    }
    if (t < SCAN_GRID) bsum[t] = (t > 0) ? s[t - 1] : 0;
}

__global__ void scan_final_kernel(int* __restrict__ cnt, const int* __restrict__ bsum) {
    __shared__ int s[SCAN_BLOCK];
    int i = blockIdx.x * SCAN_BLOCK + threadIdx.x;
    int v = (i < N_NODES) ? cnt[i] : 0;
    s[threadIdx.x] = v;
    __syncthreads();
    for (int off = 1; off < SCAN_BLOCK; off <<= 1) {
        int u = (threadIdx.x >= off) ? s[threadIdx.x - off] : 0;
        __syncthreads();
        s[threadIdx.x] += u;
        __syncthreads();
    }
    if (i < N_NODES) cnt[i] = bsum[blockIdx.x] + s[threadIdx.x] - v;
}

__global__ void scatter2_kernel(const int* __restrict__ dst,
                                const int* __restrict__ src,
                                const float* __restrict__ edge_attr,
                                int* __restrict__ pos,
                                int* __restrict__ ssrc,
                                float4* __restrict__ sea) {
    int e = blockIdx.x * blockDim.x + threadIdx.x;
    if (e < N_EDGES) {
        int p = atomicAdd(&pos[dst[e]], 1);
        ssrc[p] = src[e];
        sea[p] = ((const float4*)edge_attr)[e];
    }
}

__global__ void gather2_kernel(const float* __restrict__ x,
                               const int* __restrict__ ssrc,
                               const float4* __restrict__ sea,
                               const int* __restrict__ pos,   // pos[i]=end; start=pos[i-1]
                               const float* __restrict__ We_l,
                               const float* __restrict__ be_l,
                               float* __restrict__ h) {
    __shared__ float sWe[EDGE_CH * HIDDEN];
    __shared__ float sbe[HIDDEN];
    for (int i = threadIdx.x; i < EDGE_CH * HIDDEN; i += blockDim.x) sWe[i] = We_l[i];
    if (threadIdx.x < HIDDEN) sbe[threadIdx.x] = be_l[threadIdx.x];
    __syncthreads();

    int t = blockIdx.x * blockDim.x + threadIdx.x;
    int node = t >> 5;
    int c4 = t & 31;
    if (node >= N_NODES) return;

    int start = (node == 0) ? 0 : pos[node - 1];
    int end = pos[node];

    float4 w0 = ((const float4*)sWe)[0 * 32 + c4];
    float4 w1 = ((const float4*)sWe)[1 * 32 + c4];
    float4 w2 = ((const float4*)sWe)[2 * 32 + c4];
    float4 w3 = ((const float4*)sWe)[3 * 32 + c4];
    float4 bb = ((const float4*)sbe)[c4];

    float4 acc = make_float4(0.f, 0.f, 0.f, 0.f);
    int j = start;
    if (j < end) {
        int s0 = ssrc[j];
        float4 ea0 = sea[j];
        for (; j + 1 < end; j++) {
            int s1 = ssrc[j + 1];
            float4 ea1 = sea[j + 1];
            float4 xv = ((const float4*)(x + (size_t)s0 * HIDDEN))[c4];
            float m0 = xv.x + ea0.x*w0.x + ea0.y*w1.x + ea0.z*w2.x + ea0.w*w3.x + bb.x;
            float m1 = xv.y + ea0.x*w0.y + ea0.y*w1.y + ea0.z*w2.y + ea0.w*w3.y + bb.y;
            float m2 = xv.z + ea0.x*w0.z + ea0.y*w1.z + ea0.z*w2.z + ea0.w*w3.z + bb.z;
            float m3 = xv.w + ea0.x*w0.w + ea0.y*w1.w + ea0.z*w2.w + ea0.w*w3.w + bb.w;
            acc.x += fmaxf(m0, 0.f); acc.y += fmaxf(m1, 0.f);
            acc.z += fmaxf(m2, 0.f); acc.w += fmaxf(m3, 0.f);
            s0 = s1; ea0 = ea1;
        }
        float4 xv = ((const float4*)(x + (size_t)s0 * HIDDEN))[c4];
        float m0 = xv.x + ea0.x*w0.x + ea0.y*w1.x + ea0.z*w2.x + ea0.w*w3.x + bb.x;
        float m1 = xv.y + ea0.x*w0.y + ea0.y*w1.y + ea0.z*w2.y + ea0.w*w3.y + bb.y;
        float m2 = xv.z + ea0.x*w0.z + ea0.y*w1.z + ea0.z*w2.z + ea0.w*w3.z + bb.z;
        float m3 = xv.w + ea0.x*w0.w + ea0.y*w1.w + ea0.z*w2.w + ea0.w*w3.w + bb.w;
        acc.x += fmaxf(m0, 0.f); acc.y += fmaxf(m1, 0.f);
        acc.z += fmaxf(m2, 0.f); acc.w += fmaxf(m3, 0.f);
    }
    float4 xi = ((const float4*)(x + (size_t)node * HIDDEN))[c4];
    acc.x += xi.x; acc.y += xi.y; acc.z += xi.z; acc.w += xi.w;
    ((float4*)(h + (size_t)node * HIDDEN))[c4] = acc;
}

// ---------------- Level C fallback: atomics ----------------

__global__ void edge_kernel(const float* __restrict__ x,
                            const float* __restrict__ edge_attr,
                            const int* __restrict__ src,
                            const int* __restrict__ dst,
                            const float* __restrict__ We_l,
                            const float* __restrict__ be_l,
                            float* __restrict__ agg) {
    __shared__ float sWe[EDGE_CH * HIDDEN];
    __shared__ float sbe[HIDDEN];
    for (int i = threadIdx.x; i < EDGE_CH * HIDDEN; i += blockDim.x) sWe[i] = We_l[i];
    if (threadIdx.x < HIDDEN) sbe[threadIdx.x] = be_l[threadIdx.x];
    __syncthreads();

    int t = blockIdx.x * blockDim.x + threadIdx.x;
    int e = t >> 5;
    if (e >= N_EDGES) return;
    int c4 = t & 31;

    int s = src[e];
    int d = dst[e];
    float4 ea = ((const float4*)edge_attr)[e];
    float4 w0 = ((const float4*)sWe)[0 * 32 + c4];
    float4 w1 = ((const float4*)sWe)[1 * 32 + c4];
    float4 w2 = ((const float4*)sWe)[2 * 32 + c4];
    float4 w3 = ((const float4*)sWe)[3 * 32 + c4];
    float4 bb = ((const float4*)sbe)[c4];
    float4 xv = ((const float4*)(x + (size_t)s * HIDDEN))[c4];

    float m0 = xv.x + ea.x*w0.x + ea.y*w1.x + ea.z*w2.x + ea.w*w3.x + bb.x;
    float m1 = xv.y + ea.x*w0.y + ea.y*w1.y + ea.z*w2.y + ea.w*w3.y + bb.y;
    float m2 = xv.z + ea.x*w0.z + ea.y*w1.z + ea.z*w2.z + ea.w*w3.z + bb.z;
    float m3 = xv.w + ea.x*w0.w + ea.y*w1.w + ea.z*w2.w + ea.w*w3.w + bb.w;

    float* ap = agg + (size_t)d * HIDDEN + c4 * 4;
    atomicAdd(ap + 0, fmaxf(m0, 0.f));
    atomicAdd(ap + 1, fmaxf(m1, 0.f));
    atomicAdd(ap + 2, fmaxf(m2, 0.f));
    atomicAdd(ap + 3, fmaxf(m3, 0.f));
}

// ---------------- host ----------------

extern "C" void kernel_launch(void* const* d_in, const int* in_sizes, int n_in,
                              void* d_out, int out_size, void* d_ws, size_t ws_size,
                              hipStream_t stream) {
    const float* emb       = (const float*)d_in[0];
    const float* We        = (const float*)d_in[1];
    const float* be        = (const float*)d_in[2];
    const float* W1        = (const float*)d_in[3];
    const float* b1        = (const float*)d_in[4];
    const float* W2        = (const float*)d_in[5];
    const float* b2        = (const float*)d_in[6];
    const float* edge_attr = (const float*)d_in[7];
    const int*   z         = (const int*)d_in[8];
    const int*   ei        = (const int*)d_in[9];
    const int*   bv        = (const int*)d_in[10];

    float* x   = (float*)d_out;
    float* agg = (float*)d_ws;
    const int* src = ei;
    const int* dst = ei + N_EDGES;

    const size_t AGG_BYTES  = (size_t)N_NODES * HIDDEN * sizeof(float);     // 51.2 MB
    const size_t POS_BYTES  = (size_t)N_NODES * sizeof(int);                // 0.4 MB
    const size_t SRC_BYTES  = (size_t)N_EDGES * sizeof(int);                // 2.4 MB
    const size_t EA_BYTES   = (size_t)N_EDGES * 4 * sizeof(float);          // 9.6 MB
    const size_t BSUM_BYTES = ((size_t)SCAN_GRID * sizeof(int) + 15) & ~15; // 1568 B
    const size_t WT_ELEMS   = (size_t)NUM_LAYERS * 2 * HIDDEN * HIDDEN;     // 98304
    const size_t WT_BYTES   = WT_ELEMS * sizeof(unsigned short);            // 196608 B each

    const size_t OFF_POS  = AGG_BYTES;
    const size_t OFF_SRC  = OFF_POS + POS_BYTES;
    const size_t OFF_EA   = OFF_SRC + SRC_BYTES;
    const size_t OFF_BSUM = OFF_EA + EA_BYTES;
    const size_t OFF_WTHI = OFF_BSUM + BSUM_BYTES;
    const size_t OFF_WTLO = OFF_WTHI + WT_BYTES;
    const size_t TOTAL    = OFF_WTLO + WT_BYTES;

    const int MLP_GRID   = (N_NODES + MLP_ROWS - 1) / MLP_ROWS;
    const int MFMA_GRID  = (N_NODES + 63) / 64;

    if (ws_size >= OFF_BSUM + BSUM_BYTES) {
        // Level A: de-indirected CSR + parallel scan
        int*    pos  = (int*)((char*)d_ws + OFF_POS);
        int*    ssrc = (int*)((char*)d_ws + OFF_SRC);
        float4* sea  = (float4*)((char*)d_ws + OFF_EA);
        int*    bsum = (int*)((char*)d_ws + OFF_BSUM);
        const bool mfma = (ws_size >= TOTAL);
        unsigned short* wt_hi = (unsigned short*)((char*)d_ws + OFF_WTHI);
        unsigned short* wt_lo = (unsigned short*)((char*)d_ws + OFF_WTLO);

        embed_init_kernel<<<(N_NODES * 32) / 256, 256, 0, stream>>>(emb, z, x, agg, 0);
        zero_kernel<<<(N_NODES + 255) / 256, 256, 0, stream>>>(pos, N_NODES);
        hist_kernel<<<(N_EDGES + 255) / 256, 256, 0, stream>>>(dst, pos);
        scan_partial_kernel<<<SCAN_GRID, SCAN_BLOCK, 0, stream>>>(pos, bsum);
        scan_base_kernel<<<1, 512, 0, stream>>>(bsum);
        scan_final_kernel<<<SCAN_GRID, SCAN_BLOCK, 0, stream>>>(pos, bsum);
        scatter2_kernel<<<(N_EDGES + 255) / 256, 256, 0, stream>>>(dst, src, edge_attr, pos, ssrc, sea);
        if (mfma)
            wprep_kernel<<<((int)WT_ELEMS + 255) / 256, 256, 0, stream>>>(W1, W2, wt_hi, wt_lo);

        for (int l = 0; l < NUM_LAYERS; l++) {
            gather2_kernel<<<(N_NODES * 32 + 255) / 256, 256, 0, stream>>>(
                x, ssrc, sea, pos,
                We + (size_t)l * EDGE_CH * HIDDEN, be + (size_t)l * HIDDEN, agg);
            if (mfma) {
                mlp_mfma_kernel<<<MFMA_GRID, 256, 0, stream>>>(
                    agg,
                    wt_hi + (size_t)(l * 2 + 0) * HIDDEN * HIDDEN,
                    wt_lo + (size_t)(l * 2 + 0) * HIDDEN * HIDDEN,
                    wt_hi + (size_t)(l * 2 + 1) * HIDDEN * HIDDEN,
                    wt_lo + (size_t)(l * 2 + 1) * HIDDEN * HIDDEN,
                    b1 + (size_t)l * HIDDEN, b2 + (size_t)l * HIDDEN, x);
            } else {
                mlp_kernel<<<MLP_GRID, 256, 0, stream>>>(
                    agg,
                    W1 + (size_t)l * HIDDEN * HIDDEN, b1 + (size_t)l * HIDDEN,
                    W2 + (size_t)l * HIDDEN * HIDDEN, b2 + (size_t)l * HIDDEN, x);
            }
        }
    } else {
        // Level C: atomic fallback
        embed_init_kernel<<<(N_NODES * 32) / 256, 256, 0, stream>>>(emb, z, x, agg, 1);
        for (int l = 0; l < NUM_LAYERS; l++) {
            edge_kernel<<<(N_EDGES * 32) / 256, 256, 0, stream>>>(
                x, edge_attr, src, dst,
                We + (size_t)l * EDGE_CH * HIDDEN, be + (size_t)l * HIDDEN, agg);
            mlp_kernel<<<MLP_GRID, 256, 0, stream>>>(
                agg,
                W1 + (size_t)l * HIDDEN * HIDDEN, b1 + (size_t)l * HIDDEN,
                W2 + (size_t)l * HIDDEN * HIDDEN, b2 + (size_t)l * HIDDEN, x);
        }
    }

    batch_out_kernel<<<(N_NODES + 255) / 256, 256, 0, stream>>>(bv, x + (size_t)N_NODES * HIDDEN);
}

// Round 6
// 600.135 us; speedup vs baseline: 7.0933x; 1.1554x over previous
//
#include <hip/hip_runtime.h>
#include <math.h>

#define N_NODES 100000
#define N_EDGES 600000
#define HIDDEN 128
#define EDGE_CH 4
#define NUM_LAYERS 3
#define MLP_ROWS 64   // nodes per block in fp32 fallback mlp_kernel

#define SCAN_BLOCK 256
#define SCAN_GRID ((N_NODES + SCAN_BLOCK - 1) / SCAN_BLOCK)   // 391

#define HSTR 132      // padded LDS row stride (floats) for MFMA mlp

typedef short bf16x8 __attribute__((ext_vector_type(8)));
typedef float f32x4  __attribute__((ext_vector_type(4)));

__device__ inline unsigned short f2bf(float x) {           // RNE fp32 -> bf16 bits
    unsigned u = __float_as_uint(x);
    return (unsigned short)((u + 0x7fff + ((u >> 16) & 1)) >> 16);
}
__device__ inline float bf2f(unsigned short b) { return __uint_as_float(((unsigned)b) << 16); }

// ---------------- common kernels ----------------

__global__ void embed_init_kernel(const float* __restrict__ emb,
                                  const int* __restrict__ z,
                                  float* __restrict__ x,
                                  float* __restrict__ agg,
                                  int write_agg) {
    int t = blockIdx.x * blockDim.x + threadIdx.x;
    int node = t >> 5;
    int c4 = t & 31;
    if (node < N_NODES) {
        float4 v = ((const float4*)(emb + (size_t)z[node] * HIDDEN))[c4];
        ((float4*)(x + (size_t)node * HIDDEN))[c4] = v;
        if (write_agg)
            ((float4*)(agg + (size_t)node * HIDDEN))[c4] = v;
    }
}

// Pre-transpose W1/W2 (all layers) to bf16: wt[(l*2+mat)*16384 + n*128 + k]
__global__ void wprep_kernel(const float* __restrict__ W1, const float* __restrict__ W2,
                             unsigned short* __restrict__ wt) {
    int idx = blockIdx.x * blockDim.x + threadIdx.x;
    if (idx >= NUM_LAYERS * 2 * HIDDEN * HIDDEN) return;
    int k   = idx & 127;
    int n   = (idx >> 7) & 127;
    int mat = (idx >> 14) & 1;
    int l   = idx >> 15;
    const float* W = mat ? W2 : W1;
    wt[idx] = f2bf(W[(size_t)l * HIDDEN * HIDDEN + (size_t)k * HIDDEN + n]);
}

// MFMA MLP v2: x = silu(h@W1 + b1)@W2 + b2.
// A = exact fp32 as bf16 hi+lo (2 MFMAs); B = bf16 weights, all 32 fragments
// hoisted into registers. 4 waves/block, 16 nodes/wave, 64 nodes/block.
__global__ __launch_bounds__(256, 2) void mlp_mfma2_kernel(
        const float* __restrict__ h,
        const unsigned short* __restrict__ wt1,   // bf16 [n][k]
        const unsigned short* __restrict__ wt2,   // bf16 [n][k]
        const float* __restrict__ b1, const float* __restrict__ b2,
        float* __restrict__ x) {
    __shared__ float sh[4 * 16 * HSTR];          // t round-trip, per-wave region
    int wave  = threadIdx.x >> 6;
    int lane  = threadIdx.x & 63;
    int row16 = lane & 15;
    int quad  = lane >> 4;
    int wnode0 = blockIdx.x * 64 + wave * 16;
    float* myh = sh + wave * 16 * HSTR;

    // ---- B1 fragments: 8 nt x 4 ks, 16B/lane, all independent, in flight ----
    bf16x8 B[8][4];
    #pragma unroll
    for (int nt = 0; nt < 8; nt++)
        #pragma unroll
        for (int ks = 0; ks < 4; ks++)
            B[nt][ks] = *(const bf16x8*)(wt1 + (nt * 16 + row16) * HIDDEN + ks * 32 + quad * 8);

    // ---- A fragments straight from global h (lane's own 8 floats per ks) ----
    int mnode = wnode0 + row16;
    bool valid = (mnode < N_NODES);
    const float* hrow = h + (size_t)mnode * HIDDEN + quad * 8;
    bf16x8 ahi[4], alo[4];
    #pragma unroll
    for (int ks = 0; ks < 4; ks++) {
        float v[8];
        *(float4*)(v + 0) = valid ? *(const float4*)(hrow + ks * 32 + 0) : make_float4(0.f,0.f,0.f,0.f);
        *(float4*)(v + 4) = valid ? *(const float4*)(hrow + ks * 32 + 4) : make_float4(0.f,0.f,0.f,0.f);
        bf16x8 hi, lo;
        #pragma unroll
        for (int j = 0; j < 8; j++) {
            unsigned short hb = f2bf(v[j]);
            hi[j] = (short)hb;
            lo[j] = (short)f2bf(v[j] - bf2f(hb));
        }
        ahi[ks] = hi; alo[ks] = lo;
    }

    // ---- GEMM1: ks outer, nt inner -> 8 independent acc chains ----
    f32x4 acc[8];
    #pragma unroll
    for (int nt = 0; nt < 8; nt++) acc[nt] = (f32x4){0.f, 0.f, 0.f, 0.f};
    #pragma unroll
    for (int ks = 0; ks < 4; ks++) {
        #pragma unroll
        for (int nt = 0; nt < 8; nt++)
            acc[nt] = __builtin_amdgcn_mfma_f32_16x16x32_bf16(ahi[ks], B[nt][ks], acc[nt], 0, 0, 0);
        #pragma unroll
        for (int nt = 0; nt < 8; nt++)
            acc[nt] = __builtin_amdgcn_mfma_f32_16x16x32_bf16(alo[ks], B[nt][ks], acc[nt], 0, 0, 0);
    }

    // ---- bias + silu -> t in LDS (D layout: col=lane&15, row=quad*4+r) ----
    #pragma unroll
    for (int nt = 0; nt < 8; nt++) {
        float bias = b1[nt * 16 + row16];
        #pragma unroll
        for (int r = 0; r < 4; r++) {
            float v = acc[nt][r] + bias;
            v = v / (1.f + __expf(-v));
            myh[(quad * 4 + r) * HSTR + nt * 16 + row16] = v;
        }
    }
    __syncthreads();

    // ---- B2 fragments (reuse B registers) ----
    #pragma unroll
    for (int nt = 0; nt < 8; nt++)
        #pragma unroll
        for (int ks = 0; ks < 4; ks++)
            B[nt][ks] = *(const bf16x8*)(wt2 + (nt * 16 + row16) * HIDDEN + ks * 32 + quad * 8);

    // ---- A2 fragments from t in LDS ----
    #pragma unroll
    for (int ks = 0; ks < 4; ks++) {
        const float* p = myh + row16 * HSTR + ks * 32 + quad * 8;
        float v[8];
        *(float4*)(v + 0) = *(const float4*)(p + 0);
        *(float4*)(v + 4) = *(const float4*)(p + 4);
        bf16x8 hi, lo;
        #pragma unroll
        for (int j = 0; j < 8; j++) {
            unsigned short hb = f2bf(v[j]);
            hi[j] = (short)hb;
            lo[j] = (short)f2bf(v[j] - bf2f(hb));
        }
        ahi[ks] = hi; alo[ks] = lo;
    }

    // ---- GEMM2 ----
    #pragma unroll
    for (int nt = 0; nt < 8; nt++) acc[nt] = (f32x4){0.f, 0.f, 0.f, 0.f};
    #pragma unroll
    for (int ks = 0; ks < 4; ks++) {
        #pragma unroll
        for (int nt = 0; nt < 8; nt++)
            acc[nt] = __builtin_amdgcn_mfma_f32_16x16x32_bf16(ahi[ks], B[nt][ks], acc[nt], 0, 0, 0);
        #pragma unroll
        for (int nt = 0; nt < 8; nt++)
            acc[nt] = __builtin_amdgcn_mfma_f32_16x16x32_bf16(alo[ks], B[nt][ks], acc[nt], 0, 0, 0);
    }

    // ---- bias + store ----
    #pragma unroll
    for (int nt = 0; nt < 8; nt++) {
        float bias = b2[nt * 16 + row16];
        #pragma unroll
        for (int r = 0; r < 4; r++) {
            int node = wnode0 + quad * 4 + r;
            if (node < N_NODES)
                x[(size_t)node * HIDDEN + nt * 16 + row16] = acc[nt][r] + bias;
        }
    }
}

// fp32 fallback MLP
__global__ void mlp_kernel(const float* __restrict__ h,
                           const float* __restrict__ W1, const float* __restrict__ b1,
                           const float* __restrict__ W2, const float* __restrict__ b2,
                           float* __restrict__ x) {
    __shared__ float hs[MLP_ROWS * HIDDEN];
    int rg = threadIdx.x >> 5;
    int c4 = threadIdx.x & 31;
    int node0 = blockIdx.x * MLP_ROWS;

    for (int i = threadIdx.x; i < MLP_ROWS * 32; i += 256) {
        int node = node0 + (i >> 5);
        float4 v = (node < N_NODES)
                 ? ((const float4*)(h + (size_t)node * HIDDEN))[i & 31]
                 : make_float4(0.f, 0.f, 0.f, 0.f);
        ((float4*)hs)[i] = v;
    }
    __syncthreads();

    float4 acc[8];
    {
        float4 bv = ((const float4*)b1)[c4];
        #pragma unroll
        for (int r = 0; r < 8; r++) acc[r] = bv;
    }
    const float* hbase = hs + rg * 8 * HIDDEN;

    for (int k4 = 0; k4 < HIDDEN; k4 += 4) {
        float4 w0 = ((const float4*)(W1 + (size_t)(k4 + 0) * HIDDEN))[c4];
        float4 w1 = ((const float4*)(W1 + (size_t)(k4 + 1) * HIDDEN))[c4];
        float4 w2 = ((const float4*)(W1 + (size_t)(k4 + 2) * HIDDEN))[c4];
        float4 w3 = ((const float4*)(W1 + (size_t)(k4 + 3) * HIDDEN))[c4];
        #pragma unroll
        for (int r = 0; r < 8; r++) {
            float4 hv = *(const float4*)(hbase + r * HIDDEN + k4);
            acc[r].x += hv.x*w0.x + hv.y*w1.x + hv.z*w2.x + hv.w*w3.x;
            acc[r].y += hv.x*w0.y + hv.y*w1.y + hv.z*w2.y + hv.w*w3.y;
            acc[r].z += hv.x*w0.z + hv.y*w1.z + hv.z*w2.z + hv.w*w3.z;
            acc[r].w += hv.x*w0.w + hv.y*w1.w + hv.z*w2.w + hv.w*w3.w;
        }
    }

    __syncthreads();
    #pragma unroll
    for (int r = 0; r < 8; r++) {
        float4 a = acc[r];
        a.x = a.x / (1.f + __expf(-a.x));
        a.y = a.y / (1.f + __expf(-a.y));
        a.z = a.z / (1.f + __expf(-a.z));
        a.w = a.w / (1.f + __expf(-a.w));
        *(float4*)(hs + (rg * 8 + r) * HIDDEN + c4 * 4) = a;
    }
    __syncthreads();

    {
        float4 bv = ((const float4*)b2)[c4];
        #pragma unroll
        for (int r = 0; r < 8; r++) acc[r] = bv;
    }
    for (int k4 = 0; k4 < HIDDEN; k4 += 4) {
        float4 w0 = ((const float4*)(W2 + (size_t)(k4 + 0) * HIDDEN))[c4];
        float4 w1 = ((const float4*)(W2 + (size_t)(k4 + 1) * HIDDEN))[c4];
        float4 w2 = ((const float4*)(W2 + (size_t)(k4 + 2) * HIDDEN))[c4];
        float4 w3 = ((const float4*)(W2 + (size_t)(k4 + 3) * HIDDEN))[c4];
        #pragma unroll
        for (int r = 0; r < 8; r++) {
            float4 hv = *(const float4*)(hbase + r * HIDDEN + k4);
            acc[r].x += hv.x*w0.x + hv.y*w1.x + hv.z*w2.x + hv.w*w3.x;
            acc[r].y += hv.x*w0.y + hv.y*w1.y + hv.z*w2.y + hv.w*w3.y;
            acc[r].z += hv.x*w0.z + hv.y*w1.z + hv.z*w2.z + hv.w*w3.z;
            acc[r].w += hv.x*w0.w + hv.y*w1.w + hv.z*w2.w + hv.w*w3.w;
        }
    }

    #pragma unroll
    for (int r = 0; r < 8; r++) {
        int node = node0 + rg * 8 + r;
        if (node < N_NODES)
            ((float4*)(x + (size_t)node * HIDDEN))[c4] = acc[r];
    }
}

__global__ void batch_out_kernel(const int* __restrict__ bv, float* __restrict__ out) {
    int i = blockIdx.x * blockDim.x + threadIdx.x;
    if (i < N_NODES) out[i] = (float)bv[i];
}

// ---------------- CSR build ----------------

__global__ void zero_kernel(int* __restrict__ p, int n) {
    int i = blockIdx.x * blockDim.x + threadIdx.x;
    if (i < n) p[i] = 0;
}

__global__ void hist_kernel(const int* __restrict__ dst, int* __restrict__ cnt) {
    int e = blockIdx.x * blockDim.x + threadIdx.x;
    if (e < N_EDGES) atomicAdd(&cnt[dst[e]], 1);
}

__global__ void scan_partial_kernel(const int* __restrict__ cnt, int* __restrict__ bsum) {
    __shared__ int s[SCAN_BLOCK];
    int i = blockIdx.x * SCAN_BLOCK + threadIdx.x;
    s[threadIdx.x] = (i < N_NODES) ? cnt[i] : 0;
    __syncthreads();
    for (int off = SCAN_BLOCK / 2; off > 0; off >>= 1) {
        if (threadIdx.x < off) s[threadIdx.x] += s[threadIdx.x + off];
        __syncthreads();
    }
    if (threadIdx.x == 0) bsum[blockIdx.x] = s[0];
}

__global__ void scan_base_kernel(int* __restrict__ bsum) {
    __shared__ int s[512];
    int t = threadIdx.x;
    s[t] = (t < SCAN_GRID) ? bsum[t] : 0;
    __syncthreads();
    for (int off = 1; off < 512; off <<= 1) {
        int v = (t >= off) ? s[t - off] : 0;
        __syncthreads();
        s[t] += v;
        __syncthreads();
    }
    if (t < SCAN_GRID) bsum[t] = (t > 0) ? s[t - 1] : 0;
}

__global__ void scan_final_kernel(int* __restrict__ cnt, const int* __restrict__ bsum) {
    __shared__ int s[SCAN_BLOCK];
    int i = blockIdx.x * SCAN_BLOCK + threadIdx.x;
    int v = (i < N_NODES) ? cnt[i] : 0;
    s[threadIdx.x] = v;
    __syncthreads();
    for (int off = 1; off < SCAN_BLOCK; off <<= 1) {
        int u = (threadIdx.x >= off) ? s[threadIdx.x - off] : 0;
        __syncthreads();
        s[threadIdx.x] += u;
        __syncthreads();
    }
    if (i < N_NODES) cnt[i] = bsum[blockIdx.x] + s[threadIdx.x] - v;
}

__global__ void scatter2_kernel(const int* __restrict__ dst,
                                const int* __restrict__ src,
                                const float* __restrict__ edge_attr,
                                int* __restrict__ pos,
                                int* __restrict__ ssrc,
                                float4* __restrict__ sea) {
    int e = blockIdx.x * blockDim.x + threadIdx.x;
    if (e < N_EDGES) {
        int p = atomicAdd(&pos[dst[e]], 1);
        ssrc[p] = src[e];
        sea[p] = ((const float4*)edge_attr)[e];
    }
}

__global__ void gather2_kernel(const float* __restrict__ x,
                               const int* __restrict__ ssrc,
                               const float4* __restrict__ sea,
                               const int* __restrict__ pos,   // pos[i]=end; start=pos[i-1]
                               const float* __restrict__ We_l,
                               const float* __restrict__ be_l,
                               float* __restrict__ h) {
    __shared__ float sWe[EDGE_CH * HIDDEN];
    __shared__ float sbe[HIDDEN];
    for (int i = threadIdx.x; i < EDGE_CH * HIDDEN; i += blockDim.x) sWe[i] = We_l[i];
    if (threadIdx.x < HIDDEN) sbe[threadIdx.x] = be_l[threadIdx.x];
    __syncthreads();

    int t = blockIdx.x * blockDim.x + threadIdx.x;
    int node = t >> 5;
    int c4 = t & 31;
    if (node >= N_NODES) return;

    int start = (node == 0) ? 0 : pos[node - 1];
    int end = pos[node];

    float4 w0 = ((const float4*)sWe)[0 * 32 + c4];
    float4 w1 = ((const float4*)sWe)[1 * 32 + c4];
    float4 w2 = ((const float4*)sWe)[2 * 32 + c4];
    float4 w3 = ((const float4*)sWe)[3 * 32 + c4];
    float4 bb = ((const float4*)sbe)[c4];

    float4 acc = make_float4(0.f, 0.f, 0.f, 0.f);
    int j = start;
    if (j < end) {
        int s0 = ssrc[j];
        float4 ea0 = sea[j];
        for (; j + 1 < end; j++) {
            int s1 = ssrc[j + 1];
            float4 ea1 = sea[j + 1];
            float4 xv = ((const float4*)(x + (size_t)s0 * HIDDEN))[c4];
            float m0 = xv.x + ea0.x*w0.x + ea0.y*w1.x + ea0.z*w2.x + ea0.w*w3.x + bb.x;
            float m1 = xv.y + ea0.x*w0.y + ea0.y*w1.y + ea0.z*w2.y + ea0.w*w3.y + bb.y;
            float m2 = xv.z + ea0.x*w0.z + ea0.y*w1.z + ea0.z*w2.z + ea0.w*w3.z + bb.z;
            float m3 = xv.w + ea0.x*w0.w + ea0.y*w1.w + ea0.z*w2.w + ea0.w*w3.w + bb.w;
            acc.x += fmaxf(m0, 0.f); acc.y += fmaxf(m1, 0.f);
            acc.z += fmaxf(m2, 0.f); acc.w += fmaxf(m3, 0.f);
            s0 = s1; ea0 = ea1;
        }
        float4 xv = ((const float4*)(x + (size_t)s0 * HIDDEN))[c4];
        float m0 = xv.x + ea0.x*w0.x + ea0.y*w1.x + ea0.z*w2.x + ea0.w*w3.x + bb.x;
        float m1 = xv.y + ea0.x*w0.y + ea0.y*w1.y + ea0.z*w2.y + ea0.w*w3.y + bb.y;
        float m2 = xv.z + ea0.x*w0.z + ea0.y*w1.z + ea0.z*w2.z + ea0.w*w3.z + bb.z;
        float m3 = xv.w + ea0.x*w0.w + ea0.y*w1.w + ea0.z*w2.w + ea0.w*w3.w + bb.w;
        acc.x += fmaxf(m0, 0.f); acc.y += fmaxf(m1, 0.f);
        acc.z += fmaxf(m2, 0.f); acc.w += fmaxf(m3, 0.f);
    }
    float4 xi = ((const float4*)(x + (size_t)node * HIDDEN))[c4];
    acc.x += xi.x; acc.y += xi.y; acc.z += xi.z; acc.w += xi.w;
    ((float4*)(h + (size_t)node * HIDDEN))[c4] = acc;
}

// ---------------- Level C fallback: atomics ----------------

__global__ void edge_kernel(const float* __restrict__ x,
                            const float* __restrict__ edge_attr,
                            const int* __restrict__ src,
                            const int* __restrict__ dst,
                            const float* __restrict__ We_l,
                            const float* __restrict__ be_l,
                            float* __restrict__ agg) {
    __shared__ float sWe[EDGE_CH * HIDDEN];
    __shared__ float sbe[HIDDEN];
    for (int i = threadIdx.x; i < EDGE_CH * HIDDEN; i += blockDim.x) sWe[i] = We_l[i];
    if (threadIdx.x < HIDDEN) sbe[threadIdx.x] = be_l[threadIdx.x];
    __syncthreads();

    int t = blockIdx.x * blockDim.x + threadIdx.x;
    int e = t >> 5;
    if (e >= N_EDGES) return;
    int c4 = t & 31;

    int s = src[e];
    int d = dst[e];
    float4 ea = ((const float4*)edge_attr)[e];
    float4 w0 = ((const float4*)sWe)[0 * 32 + c4];
    float4 w1 = ((const float4*)sWe)[1 * 32 + c4];
    float4 w2 = ((const float4*)sWe)[2 * 32 + c4];
    float4 w3 = ((const float4*)sWe)[3 * 32 + c4];
    float4 bb = ((const float4*)sbe)[c4];
    float4 xv = ((const float4*)(x + (size_t)s * HIDDEN))[c4];

    float m0 = xv.x + ea.x*w0.x + ea.y*w1.x + ea.z*w2.x + ea.w*w3.x + bb.x;
    float m1 = xv.y + ea.x*w0.y + ea.y*w1.y + ea.z*w2.y + ea.w*w3.y + bb.y;
    float m2 = xv.z + ea.x*w0.z + ea.y*w1.z + ea.z*w2.z + ea.w*w3.z + bb.z;
    float m3 = xv.w + ea.x*w0.w + ea.y*w1.w + ea.z*w2.w + ea.w*w3.w + bb.w;

    float* ap = agg + (size_t)d * HIDDEN + c4 * 4;
    atomicAdd(ap + 0, fmaxf(m0, 0.f));
    atomicAdd(ap + 1, fmaxf(m1, 0.f));
    atomicAdd(ap + 2, fmaxf(m2, 0.f));
    atomicAdd(ap + 3, fmaxf(m3, 0.f));
}

// ---------------- host ----------------

extern "C" void kernel_launch(void* const* d_in, const int* in_sizes, int n_in,
                              void* d_out, int out_size, void* d_ws, size_t ws_size,
                              hipStream_t stream) {
    const float* emb       = (const float*)d_in[0];
    const float* We        = (const float*)d_in[1];
    const float* be        = (const float*)d_in[2];
    const float* W1        = (const float*)d_in[3];
    const float* b1        = (const float*)d_in[4];
    const float* W2        = (const float*)d_in[5];
    const float* b2        = (const float*)d_in[6];
    const float* edge_attr = (const float*)d_in[7];
    const int*   z         = (const int*)d_in[8];
    const int*   ei        = (const int*)d_in[9];
    const int*   bv        = (const int*)d_in[10];

    float* x   = (float*)d_out;
    float* agg = (float*)d_ws;
    const int* src = ei;
    const int* dst = ei + N_EDGES;

    const size_t AGG_BYTES  = (size_t)N_NODES * HIDDEN * sizeof(float);     // 51.2 MB
    const size_t POS_BYTES  = (size_t)N_NODES * sizeof(int);                // 0.4 MB
    const size_t SRC_BYTES  = (size_t)N_EDGES * sizeof(int);                // 2.4 MB
    const size_t EA_BYTES   = (size_t)N_EDGES * 4 * sizeof(float);          // 9.6 MB
    const size_t BSUM_BYTES = ((size_t)SCAN_GRID * sizeof(int) + 15) & ~15; // 1568 B
    const size_t WT_ELEMS   = (size_t)NUM_LAYERS * 2 * HIDDEN * HIDDEN;     // 98304
    const size_t WT_BYTES   = WT_ELEMS * sizeof(unsigned short);            // 196608 B

    const size_t OFF_POS  = AGG_BYTES;
    const size_t OFF_SRC  = OFF_POS + POS_BYTES;
    const size_t OFF_EA   = OFF_SRC + SRC_BYTES;
    const size_t OFF_BSUM = OFF_EA + EA_BYTES;
    const size_t OFF_WT   = OFF_BSUM + BSUM_BYTES;
    const size_t TOTAL    = OFF_WT + WT_BYTES;

    const int MLP_GRID   = (N_NODES + MLP_ROWS - 1) / MLP_ROWS;
    const int MFMA_GRID  = (N_NODES + 63) / 64;

    if (ws_size >= OFF_BSUM + BSUM_BYTES) {
        // Level A: de-indirected CSR + parallel scan
        int*    pos  = (int*)((char*)d_ws + OFF_POS);
        int*    ssrc = (int*)((char*)d_ws + OFF_SRC);
        float4* sea  = (float4*)((char*)d_ws + OFF_EA);
        int*    bsum = (int*)((char*)d_ws + OFF_BSUM);
        const bool mfma = (ws_size >= TOTAL);
        unsigned short* wt = (unsigned short*)((char*)d_ws + OFF_WT);

        embed_init_kernel<<<(N_NODES * 32) / 256, 256, 0, stream>>>(emb, z, x, agg, 0);
        zero_kernel<<<(N_NODES + 255) / 256, 256, 0, stream>>>(pos, N_NODES);
        hist_kernel<<<(N_EDGES + 255) / 256, 256, 0, stream>>>(dst, pos);
        scan_partial_kernel<<<SCAN_GRID, SCAN_BLOCK, 0, stream>>>(pos, bsum);
        scan_base_kernel<<<1, 512, 0, stream>>>(bsum);
        scan_final_kernel<<<SCAN_GRID, SCAN_BLOCK, 0, stream>>>(pos, bsum);
        scatter2_kernel<<<(N_EDGES + 255) / 256, 256, 0, stream>>>(dst, src, edge_attr, pos, ssrc, sea);
        if (mfma)
            wprep_kernel<<<((int)WT_ELEMS + 255) / 256, 256, 0, stream>>>(W1, W2, wt);

        for (int l = 0; l < NUM_LAYERS; l++) {
            gather2_kernel<<<(N_NODES * 32 + 255) / 256, 256, 0, stream>>>(
                x, ssrc, sea, pos,
                We + (size_t)l * EDGE_CH * HIDDEN, be + (size_t)l * HIDDEN, agg);
            if (mfma) {
                mlp_mfma2_kernel<<<MFMA_GRID, 256, 0, stream>>>(
                    agg,
                    wt + (size_t)(l * 2 + 0) * HIDDEN * HIDDEN,
                    wt + (size_t)(l * 2 + 1) * HIDDEN * HIDDEN,
                    b1 + (size_t)l * HIDDEN, b2 + (size_t)l * HIDDEN, x);
            } else {
                mlp_kernel<<<MLP_GRID, 256, 0, stream>>>(
                    agg,
                    W1 + (size_t)l * HIDDEN * HIDDEN, b1 + (size_t)l * HIDDEN,
                    W2 + (size_t)l * HIDDEN * HIDDEN, b2 + (size_t)l * HIDDEN, x);
            }
        }
    } else {
        // Level C: atomic fallback
        embed_init_kernel<<<(N_NODES * 32) / 256, 256, 0, stream>>>(emb, z, x, agg, 1);
        for (int l = 0; l < NUM_LAYERS; l++) {
            edge_kernel<<<(N_EDGES * 32) / 256, 256, 0, stream>>>(
                x, edge_attr, src, dst,
                We + (size_t)l * EDGE_CH * HIDDEN, be + (size_t)l * HIDDEN, agg);
            mlp_kernel<<<MLP_GRID, 256, 0, stream>>>(
                agg,
                W1 + (size_t)l * HIDDEN * HIDDEN, b1 + (size_t)l * HIDDEN,
                W2 + (size_t)l * HIDDEN * HIDDEN, b2 + (size_t)l * HIDDEN, x);
        }
    }

    batch_out_kernel<<<(N_NODES + 255) / 256, 256, 0, stream>>>(bv, x + (size_t)N_NODES * HIDDEN);
}

// Round 7
// 446.884 us; speedup vs baseline: 9.5258x; 1.3429x over previous
//
#include <hip/hip_runtime.h>
#include <math.h>

#define N_NODES 100000
#define N_EDGES 600000
#define HIDDEN 128
#define EDGE_CH 4
#define NUM_LAYERS 3
#define MLP_ROWS 64   // nodes per block in fp32 fallback mlp_kernel

#define SCAN_BLOCK 256
#define SCAN_GRID ((N_NODES + SCAN_BLOCK - 1) / SCAN_BLOCK)   // 391

#define HSTR 132            // padded LDS row stride (floats) for silu transpose
#define MLP3_TILES ((N_NODES + 127) / 128)   // 782
#define MLP3_GRID 256       // 1 block/CU (LDS-bound), grid-stride over tiles

typedef short bf16x8 __attribute__((ext_vector_type(8)));
typedef float f32x4  __attribute__((ext_vector_type(4)));

__device__ inline unsigned short f2bf(float x) {           // RNE fp32 -> bf16 bits
    unsigned u = __float_as_uint(x);
    return (unsigned short)((u + 0x7fff + ((u >> 16) & 1)) >> 16);
}
__device__ inline float bf2f(unsigned short b) { return __uint_as_float(((unsigned)b) << 16); }

// ---------------- common kernels ----------------

__global__ void embed_init_kernel(const float* __restrict__ emb,
                                  const int* __restrict__ z,
                                  float* __restrict__ x,
                                  float* __restrict__ agg,
                                  int write_agg) {
    int t = blockIdx.x * blockDim.x + threadIdx.x;
    int node = t >> 5;
    int c4 = t & 31;
    if (node < N_NODES) {
        float4 v = ((const float4*)(emb + (size_t)z[node] * HIDDEN))[c4];
        ((float4*)(x + (size_t)node * HIDDEN))[c4] = v;
        if (write_agg)
            ((float4*)(agg + (size_t)node * HIDDEN))[c4] = v;
    }
}

// Build MFMA-fragment-ordered bf16 weight image:
// wt[ ((l*2+mat)*8 + nt)*4 + ks ][lane][j]  =  W[l][k][n],
//   n = nt*16 + (lane&15), k = ks*32 + (lane>>4)*8 + j.
// Then LDS staging in the MLP is a straight linear copy and every ds_read_b128
// is contiguous 16B/lane (conflict-free).
__global__ void wprep_kernel(const float* __restrict__ W1, const float* __restrict__ W2,
                             unsigned short* __restrict__ wt) {
    int idx = blockIdx.x * blockDim.x + threadIdx.x;
    if (idx >= NUM_LAYERS * 2 * HIDDEN * HIDDEN) return;
    int j    = idx & 7;
    int lane = (idx >> 3) & 63;
    int ks   = (idx >> 9) & 3;
    int nt   = (idx >> 11) & 7;
    int mat  = (idx >> 14) & 1;
    int l    = idx >> 15;
    int n = nt * 16 + (lane & 15);
    int k = ks * 32 + (lane >> 4) * 8 + j;
    const float* W = mat ? W2 : W1;
    wt[idx] = f2bf(W[(size_t)l * HIDDEN * HIDDEN + (size_t)k * HIDDEN + n]);
}

// MFMA MLP v3: weights in LDS (shared by 8 waves), no block barriers in the
// main loop (silu transpose uses a wave-private LDS region; wave-synchronous).
// A = exact fp32 as bf16 hi+lo (2 MFMAs per fragment); B = bf16 from LDS.
__global__ __launch_bounds__(512, 1) void mlp_mfma3_kernel(
        const float* __restrict__ h,
        const unsigned short* __restrict__ wfrag,  // this layer's [2][8][4][64][8] image
        const float* __restrict__ b1, const float* __restrict__ b2,
        float* __restrict__ x) {
    __shared__ short wlds[2 * 16384];              // 64 KB: both matrices, fragment order
    __shared__ float tbuf[8 * 16 * HSTR];          // 67.6 KB: per-wave transpose buffers
    int tid   = threadIdx.x;
    int wave  = tid >> 6;
    int lane  = tid & 63;
    int row16 = lane & 15;
    int quad  = lane >> 4;
    float* myt = tbuf + wave * 16 * HSTR;

    // stage both weight images linearly (4096 float4)
    for (int i = tid; i < 4096; i += 512)
        ((float4*)wlds)[i] = ((const float4*)wfrag)[i];
    __syncthreads();                               // only barrier in the kernel

    // per-lane biases (column = nt*16+row16), hoisted out of the tile loop
    float bias1[8], bias2[8];
    #pragma unroll
    for (int nt = 0; nt < 8; nt++) {
        bias1[nt] = b1[nt * 16 + row16];
        bias2[nt] = b2[nt * 16 + row16];
    }

    for (int tile = blockIdx.x; tile < MLP3_TILES; tile += gridDim.x) {
        int wnode0 = tile * 128 + wave * 16;
        int mnode  = wnode0 + row16;
        bool valid = (mnode < N_NODES);
        const float* hrow = h + (size_t)(valid ? mnode : 0) * HIDDEN + quad * 8;

        // ---- A1 fragments straight from global h ----
        bf16x8 ahi[4], alo[4];
        #pragma unroll
        for (int ks = 0; ks < 4; ks++) {
            float v[8];
            *(float4*)(v + 0) = valid ? *(const float4*)(hrow + ks * 32 + 0) : make_float4(0.f,0.f,0.f,0.f);
            *(float4*)(v + 4) = valid ? *(const float4*)(hrow + ks * 32 + 4) : make_float4(0.f,0.f,0.f,0.f);
            bf16x8 hi, lo;
            #pragma unroll
            for (int j = 0; j < 8; j++) {
                unsigned short hb = f2bf(v[j]);
                hi[j] = (short)hb;
                lo[j] = (short)f2bf(v[j] - bf2f(hb));
            }
            ahi[ks] = hi; alo[ks] = lo;
        }

        // ---- GEMM1: B from LDS at point of use, 8 independent acc chains ----
        f32x4 acc[8];
        #pragma unroll
        for (int nt = 0; nt < 8; nt++) acc[nt] = (f32x4){0.f, 0.f, 0.f, 0.f};
        #pragma unroll
        for (int ks = 0; ks < 4; ks++) {
            #pragma unroll
            for (int nt = 0; nt < 8; nt++) {
                bf16x8 Bv = *(const bf16x8*)(wlds + (size_t)((nt * 4 + ks) * 64 + lane) * 8);
                acc[nt] = __builtin_amdgcn_mfma_f32_16x16x32_bf16(ahi[ks], Bv, acc[nt], 0, 0, 0);
                acc[nt] = __builtin_amdgcn_mfma_f32_16x16x32_bf16(alo[ks], Bv, acc[nt], 0, 0, 0);
            }
        }

        // ---- bias + silu -> wave-private LDS (D: col=lane&15, row=quad*4+r) ----
        #pragma unroll
        for (int nt = 0; nt < 8; nt++) {
            #pragma unroll
            for (int r = 0; r < 4; r++) {
                float v = acc[nt][r] + bias1[nt];
                v = v / (1.f + __expf(-v));
                myt[(quad * 4 + r) * HSTR + nt * 16 + row16] = v;
            }
        }
        // wave-synchronous: same wave reads below; lgkmcnt ordering suffices

        // ---- A2 fragments from wave-private LDS ----
        #pragma unroll
        for (int ks = 0; ks < 4; ks++) {
            const float* p = myt + row16 * HSTR + ks * 32 + quad * 8;
            float v[8];
            *(float4*)(v + 0) = *(const float4*)(p + 0);
            *(float4*)(v + 4) = *(const float4*)(p + 4);
            bf16x8 hi, lo;
            #pragma unroll
            for (int j = 0; j < 8; j++) {
                unsigned short hb = f2bf(v[j]);
                hi[j] = (short)hb;
                lo[j] = (short)f2bf(v[j] - bf2f(hb));
            }
            ahi[ks] = hi; alo[ks] = lo;
        }

        // ---- GEMM2 ----
        #pragma unroll
        for (int nt = 0; nt < 8; nt++) acc[nt] = (f32x4){0.f, 0.f, 0.f, 0.f};
        #pragma unroll
        for (int ks = 0; ks < 4; ks++) {
            #pragma unroll
            for (int nt = 0; nt < 8; nt++) {
                bf16x8 Bv = *(const bf16x8*)(wlds + (size_t)(16384 + ((nt * 4 + ks) * 64 + lane) * 8));
                acc[nt] = __builtin_amdgcn_mfma_f32_16x16x32_bf16(ahi[ks], Bv, acc[nt], 0, 0, 0);
                acc[nt] = __builtin_amdgcn_mfma_f32_16x16x32_bf16(alo[ks], Bv, acc[nt], 0, 0, 0);
            }
        }

        // ---- bias + store ----
        #pragma unroll
        for (int nt = 0; nt < 8; nt++) {
            #pragma unroll
            for (int r = 0; r < 4; r++) {
                int node = wnode0 + quad * 4 + r;
                if (node < N_NODES)
                    x[(size_t)node * HIDDEN + nt * 16 + row16] = acc[nt][r] + bias2[nt];
            }
        }
    }
}

// fp32 fallback MLP
__global__ void mlp_kernel(const float* __restrict__ h,
                           const float* __restrict__ W1, const float* __restrict__ b1,
                           const float* __restrict__ W2, const float* __restrict__ b2,
                           float* __restrict__ x) {
    __shared__ float hs[MLP_ROWS * HIDDEN];
    int rg = threadIdx.x >> 5;
    int c4 = threadIdx.x & 31;
    int node0 = blockIdx.x * MLP_ROWS;

    for (int i = threadIdx.x; i < MLP_ROWS * 32; i += 256) {
        int node = node0 + (i >> 5);
        float4 v = (node < N_NODES)
                 ? ((const float4*)(h + (size_t)node * HIDDEN))[i & 31]
                 : make_float4(0.f, 0.f, 0.f, 0.f);
        ((float4*)hs)[i] = v;
    }
    __syncthreads();

    float4 acc[8];
    {
        float4 bv = ((const float4*)b1)[c4];
        #pragma unroll
        for (int r = 0; r < 8; r++) acc[r] = bv;
    }
    const float* hbase = hs + rg * 8 * HIDDEN;

    for (int k4 = 0; k4 < HIDDEN; k4 += 4) {
        float4 w0 = ((const float4*)(W1 + (size_t)(k4 + 0) * HIDDEN))[c4];
        float4 w1 = ((const float4*)(W1 + (size_t)(k4 + 1) * HIDDEN))[c4];
        float4 w2 = ((const float4*)(W1 + (size_t)(k4 + 2) * HIDDEN))[c4];
        float4 w3 = ((const float4*)(W1 + (size_t)(k4 + 3) * HIDDEN))[c4];
        #pragma unroll
        for (int r = 0; r < 8; r++) {
            float4 hv = *(const float4*)(hbase + r * HIDDEN + k4);
            acc[r].x += hv.x*w0.x + hv.y*w1.x + hv.z*w2.x + hv.w*w3.x;
            acc[r].y += hv.x*w0.y + hv.y*w1.y + hv.z*w2.y + hv.w*w3.y;
            acc[r].z += hv.x*w0.z + hv.y*w1.z + hv.z*w2.z + hv.w*w3.z;
            acc[r].w += hv.x*w0.w + hv.y*w1.w + hv.z*w2.w + hv.w*w3.w;
        }
    }

    __syncthreads();
    #pragma unroll
    for (int r = 0; r < 8; r++) {
        float4 a = acc[r];
        a.x = a.x / (1.f + __expf(-a.x));
        a.y = a.y / (1.f + __expf(-a.y));
        a.z = a.z / (1.f + __expf(-a.z));
        a.w = a.w / (1.f + __expf(-a.w));
        *(float4*)(hs + (rg * 8 + r) * HIDDEN + c4 * 4) = a;
    }
    __syncthreads();

    {
        float4 bv = ((const float4*)b2)[c4];
        #pragma unroll
        for (int r = 0; r < 8; r++) acc[r] = bv;
    }
    for (int k4 = 0; k4 < HIDDEN; k4 += 4) {
        float4 w0 = ((const float4*)(W2 + (size_t)(k4 + 0) * HIDDEN))[c4];
        float4 w1 = ((const float4*)(W2 + (size_t)(k4 + 1) * HIDDEN))[c4];
        float4 w2 = ((const float4*)(W2 + (size_t)(k4 + 2) * HIDDEN))[c4];
        float4 w3 = ((const float4*)(W2 + (size_t)(k4 + 3) * HIDDEN))[c4];
        #pragma unroll
        for (int r = 0; r < 8; r++) {
            float4 hv = *(const float4*)(hbase + r * HIDDEN + k4);
            acc[r].x += hv.x*w0.x + hv.y*w1.x + hv.z*w2.x + hv.w*w3.x;
            acc[r].y += hv.x*w0.y + hv.y*w1.y + hv.z*w2.y + hv.w*w3.y;
            acc[r].z += hv.x*w0.z + hv.y*w1.z + hv.z*w2.z + hv.w*w3.z;
            acc[r].w += hv.x*w0.w + hv.y*w1.w + hv.z*w2.w + hv.w*w3.w;
        }
    }

    #pragma unroll
    for (int r = 0; r < 8; r++) {
        int node = node0 + rg * 8 + r;
        if (node < N_NODES)
            ((float4*)(x + (size_t)node * HIDDEN))[c4] = acc[r];
    }
}

__global__ void batch_out_kernel(const int* __restrict__ bv, float* __restrict__ out) {
    int i = blockIdx.x * blockDim.x + threadIdx.x;
    if (i < N_NODES) out[i] = (float)bv[i];
}

// ---------------- CSR build ----------------

__global__ void zero_kernel(int* __restrict__ p, int n) {
    int i = blockIdx.x * blockDim.x + threadIdx.x;
    if (i < n) p[i] = 0;
}

__global__ void hist_kernel(const int* __restrict__ dst, int* __restrict__ cnt) {
    int e = blockIdx.x * blockDim.x + threadIdx.x;
    if (e < N_EDGES) atomicAdd(&cnt[dst[e]], 1);
}

__global__ void scan_partial_kernel(const int* __restrict__ cnt, int* __restrict__ bsum) {
    __shared__ int s[SCAN_BLOCK];
    int i = blockIdx.x * SCAN_BLOCK + threadIdx.x;
    s[threadIdx.x] = (i < N_NODES) ? cnt[i] : 0;
    __syncthreads();
    for (int off = SCAN_BLOCK / 2; off > 0; off >>= 1) {
        if (threadIdx.x < off) s[threadIdx.x] += s[threadIdx.x + off];
        __syncthreads();
    }
    if (threadIdx.x == 0) bsum[blockIdx.x] = s[0];
}

__global__ void scan_base_kernel(int* __restrict__ bsum) {
    __shared__ int s[512];
    int t = threadIdx.x;
    s[t] = (t < SCAN_GRID) ? bsum[t] : 0;
    __syncthreads();
    for (int off = 1; off < 512; off <<= 1) {
        int v = (t >= off) ? s[t - off] : 0;
        __syncthreads();
        s[t] += v;
        __syncthreads();
    }
    if (t < SCAN_GRID) bsum[t] = (t > 0) ? s[t - 1] : 0;
}

__global__ void scan_final_kernel(int* __restrict__ cnt, const int* __restrict__ bsum) {
    __shared__ int s[SCAN_BLOCK];
    int i = blockIdx.x * SCAN_BLOCK + threadIdx.x;
    int v = (i < N_NODES) ? cnt[i] : 0;
    s[threadIdx.x] = v;
    __syncthreads();
    for (int off = 1; off < SCAN_BLOCK; off <<= 1) {
        int u = (threadIdx.x >= off) ? s[threadIdx.x - off] : 0;
        __syncthreads();
        s[threadIdx.x] += u;
        __syncthreads();
    }
    if (i < N_NODES) cnt[i] = bsum[blockIdx.x] + s[threadIdx.x] - v;
}

__global__ void scatter2_kernel(const int* __restrict__ dst,
                                const int* __restrict__ src,
                                const float* __restrict__ edge_attr,
                                int* __restrict__ pos,
                                int* __restrict__ ssrc,
                                float4* __restrict__ sea) {
    int e = blockIdx.x * blockDim.x + threadIdx.x;
    if (e < N_EDGES) {
        int p = atomicAdd(&pos[dst[e]], 1);
        ssrc[p] = src[e];
        sea[p] = ((const float4*)edge_attr)[e];
    }
}

__global__ void gather2_kernel(const float* __restrict__ x,
                               const int* __restrict__ ssrc,
                               const float4* __restrict__ sea,
                               const int* __restrict__ pos,   // pos[i]=end; start=pos[i-1]
                               const float* __restrict__ We_l,
                               const float* __restrict__ be_l,
                               float* __restrict__ h) {
    __shared__ float sWe[EDGE_CH * HIDDEN];
    __shared__ float sbe[HIDDEN];
    for (int i = threadIdx.x; i < EDGE_CH * HIDDEN; i += blockDim.x) sWe[i] = We_l[i];
    if (threadIdx.x < HIDDEN) sbe[threadIdx.x] = be_l[threadIdx.x];
    __syncthreads();

    int t = blockIdx.x * blockDim.x + threadIdx.x;
    int node = t >> 5;
    int c4 = t & 31;
    if (node >= N_NODES) return;

    int start = (node == 0) ? 0 : pos[node - 1];
    int end = pos[node];

    float4 w0 = ((const float4*)sWe)[0 * 32 + c4];
    float4 w1 = ((const float4*)sWe)[1 * 32 + c4];
    float4 w2 = ((const float4*)sWe)[2 * 32 + c4];
    float4 w3 = ((const float4*)sWe)[3 * 32 + c4];
    float4 bb = ((const float4*)sbe)[c4];

    float4 acc = make_float4(0.f, 0.f, 0.f, 0.f);
    int j = start;
    if (j < end) {
        int s0 = ssrc[j];
        float4 ea0 = sea[j];
        for (; j + 1 < end; j++) {
            int s1 = ssrc[j + 1];
            float4 ea1 = sea[j + 1];
            float4 xv = ((const float4*)(x + (size_t)s0 * HIDDEN))[c4];
            float m0 = xv.x + ea0.x*w0.x + ea0.y*w1.x + ea0.z*w2.x + ea0.w*w3.x + bb.x;
            float m1 = xv.y + ea0.x*w0.y + ea0.y*w1.y + ea0.z*w2.y + ea0.w*w3.y + bb.y;
            float m2 = xv.z + ea0.x*w0.z + ea0.y*w1.z + ea0.z*w2.z + ea0.w*w3.z + bb.z;
            float m3 = xv.w + ea0.x*w0.w + ea0.y*w1.w + ea0.z*w2.w + ea0.w*w3.w + bb.w;
            acc.x += fmaxf(m0, 0.f); acc.y += fmaxf(m1, 0.f);
            acc.z += fmaxf(m2, 0.f); acc.w += fmaxf(m3, 0.f);
            s0 = s1; ea0 = ea1;
        }
        float4 xv = ((const float4*)(x + (size_t)s0 * HIDDEN))[c4];
        float m0 = xv.x + ea0.x*w0.x + ea0.y*w1.x + ea0.z*w2.x + ea0.w*w3.x + bb.x;
        float m1 = xv.y + ea0.x*w0.y + ea0.y*w1.y + ea0.z*w2.y + ea0.w*w3.y + bb.y;
        float m2 = xv.z + ea0.x*w0.z + ea0.y*w1.z + ea0.z*w2.z + ea0.w*w3.z + bb.z;
        float m3 = xv.w + ea0.x*w0.w + ea0.y*w1.w + ea0.z*w2.w + ea0.w*w3.w + bb.w;
        acc.x += fmaxf(m0, 0.f); acc.y += fmaxf(m1, 0.f);
        acc.z += fmaxf(m2, 0.f); acc.w += fmaxf(m3, 0.f);
    }
    float4 xi = ((const float4*)(x + (size_t)node * HIDDEN))[c4];
    acc.x += xi.x; acc.y += xi.y; acc.z += xi.z; acc.w += xi.w;
    ((float4*)(h + (size_t)node * HIDDEN))[c4] = acc;
}

// ---------------- Level C fallback: atomics ----------------

__global__ void edge_kernel(const float* __restrict__ x,
                            const float* __restrict__ edge_attr,
                            const int* __restrict__ src,
                            const int* __restrict__ dst,
                            const float* __restrict__ We_l,
                            const float* __restrict__ be_l,
                            float* __restrict__ agg) {
    __shared__ float sWe[EDGE_CH * HIDDEN];
    __shared__ float sbe[HIDDEN];
    for (int i = threadIdx.x; i < EDGE_CH * HIDDEN; i += blockDim.x) sWe[i] = We_l[i];
    if (threadIdx.x < HIDDEN) sbe[threadIdx.x] = be_l[threadIdx.x];
    __syncthreads();

    int t = blockIdx.x * blockDim.x + threadIdx.x;
    int e = t >> 5;
    if (e >= N_EDGES) return;
    int c4 = t & 31;

    int s = src[e];
    int d = dst[e];
    float4 ea = ((const float4*)edge_attr)[e];
    float4 w0 = ((const float4*)sWe)[0 * 32 + c4];
    float4 w1 = ((const float4*)sWe)[1 * 32 + c4];
    float4 w2 = ((const float4*)sWe)[2 * 32 + c4];
    float4 w3 = ((const float4*)sWe)[3 * 32 + c4];
    float4 bb = ((const float4*)sbe)[c4];
    float4 xv = ((const float4*)(x + (size_t)s * HIDDEN))[c4];

    float m0 = xv.x + ea.x*w0.x + ea.y*w1.x + ea.z*w2.x + ea.w*w3.x + bb.x;
    float m1 = xv.y + ea.x*w0.y + ea.y*w1.y + ea.z*w2.y + ea.w*w3.y + bb.y;
    float m2 = xv.z + ea.x*w0.z + ea.y*w1.z + ea.z*w2.z + ea.w*w3.z + bb.z;
    float m3 = xv.w + ea.x*w0.w + ea.y*w1.w + ea.z*w2.w + ea.w*w3.w + bb.w;

    float* ap = agg + (size_t)d * HIDDEN + c4 * 4;
    atomicAdd(ap + 0, fmaxf(m0, 0.f));
    atomicAdd(ap + 1, fmaxf(m1, 0.f));
    atomicAdd(ap + 2, fmaxf(m2, 0.f));
    atomicAdd(ap + 3, fmaxf(m3, 0.f));
}

// ---------------- host ----------------

extern "C" void kernel_launch(void* const* d_in, const int* in_sizes, int n_in,
                              void* d_out, int out_size, void* d_ws, size_t ws_size,
                              hipStream_t stream) {
    const float* emb       = (const float*)d_in[0];
    const float* We        = (const float*)d_in[1];
    const float* be        = (const float*)d_in[2];
    const float* W1        = (const float*)d_in[3];
    const float* b1        = (const float*)d_in[4];
    const float* W2        = (const float*)d_in[5];
    const float* b2        = (const float*)d_in[6];
    const float* edge_attr = (const float*)d_in[7];
    const int*   z         = (const int*)d_in[8];
    const int*   ei        = (const int*)d_in[9];
    const int*   bv        = (const int*)d_in[10];

    float* x   = (float*)d_out;
    float* agg = (float*)d_ws;
    const int* src = ei;
    const int* dst = ei + N_EDGES;

    const size_t AGG_BYTES  = (size_t)N_NODES * HIDDEN * sizeof(float);     // 51.2 MB
    const size_t POS_BYTES  = (size_t)N_NODES * sizeof(int);                // 0.4 MB
    const size_t SRC_BYTES  = (size_t)N_EDGES * sizeof(int);                // 2.4 MB
    const size_t EA_BYTES   = (size_t)N_EDGES * 4 * sizeof(float);          // 9.6 MB
    const size_t BSUM_BYTES = ((size_t)SCAN_GRID * sizeof(int) + 15) & ~15; // 1568 B
    const size_t WT_ELEMS   = (size_t)NUM_LAYERS * 2 * HIDDEN * HIDDEN;     // 98304
    const size_t WT_BYTES   = WT_ELEMS * sizeof(unsigned short);            // 196608 B

    const size_t OFF_POS  = AGG_BYTES;
    const size_t OFF_SRC  = OFF_POS + POS_BYTES;
    const size_t OFF_EA   = OFF_SRC + SRC_BYTES;
    const size_t OFF_BSUM = OFF_EA + EA_BYTES;
    const size_t OFF_WT   = OFF_BSUM + BSUM_BYTES;
    const size_t TOTAL    = OFF_WT + WT_BYTES;

    const int MLP_GRID = (N_NODES + MLP_ROWS - 1) / MLP_ROWS;

    if (ws_size >= OFF_BSUM + BSUM_BYTES) {
        // Level A: de-indirected CSR + parallel scan
        int*    pos  = (int*)((char*)d_ws + OFF_POS);
        int*    ssrc = (int*)((char*)d_ws + OFF_SRC);
        float4* sea  = (float4*)((char*)d_ws + OFF_EA);
        int*    bsum = (int*)((char*)d_ws + OFF_BSUM);
        const bool mfma = (ws_size >= TOTAL);
        unsigned short* wt = (unsigned short*)((char*)d_ws + OFF_WT);

        embed_init_kernel<<<(N_NODES * 32) / 256, 256, 0, stream>>>(emb, z, x, agg, 0);
        zero_kernel<<<(N_NODES + 255) / 256, 256, 0, stream>>>(pos, N_NODES);
        hist_kernel<<<(N_EDGES + 255) / 256, 256, 0, stream>>>(dst, pos);
        scan_partial_kernel<<<SCAN_GRID, SCAN_BLOCK, 0, stream>>>(pos, bsum);
        scan_base_kernel<<<1, 512, 0, stream>>>(bsum);
        scan_final_kernel<<<SCAN_GRID, SCAN_BLOCK, 0, stream>>>(pos, bsum);
        scatter2_kernel<<<(N_EDGES + 255) / 256, 256, 0, stream>>>(dst, src, edge_attr, pos, ssrc, sea);
        if (mfma)
            wprep_kernel<<<((int)WT_ELEMS + 255) / 256, 256, 0, stream>>>(W1, W2, wt);

        for (int l = 0; l < NUM_LAYERS; l++) {
            gather2_kernel<<<(N_NODES * 32 + 255) / 256, 256, 0, stream>>>(
                x, ssrc, sea, pos,
                We + (size_t)l * EDGE_CH * HIDDEN, be + (size_t)l * HIDDEN, agg);
            if (mfma) {
                mlp_mfma3_kernel<<<MLP3_GRID, 512, 0, stream>>>(
                    agg,
                    wt + (size_t)(l * 2) * HIDDEN * HIDDEN,
                    b1 + (size_t)l * HIDDEN, b2 + (size_t)l * HIDDEN, x);
            } else {
                mlp_kernel<<<MLP_GRID, 256, 0, stream>>>(
                    agg,
                    W1 + (size_t)l * HIDDEN * HIDDEN, b1 + (size_t)l * HIDDEN,
                    W2 + (size_t)l * HIDDEN * HIDDEN, b2 + (size_t)l * HIDDEN, x);
            }
        }
    } else {
        // Level C: atomic fallback
        embed_init_kernel<<<(N_NODES * 32) / 256, 256, 0, stream>>>(emb, z, x, agg, 1);
        for (int l = 0; l < NUM_LAYERS; l++) {
            edge_kernel<<<(N_EDGES * 32) / 256, 256, 0, stream>>>(
                x, edge_attr, src, dst,
                We + (size_t)l * EDGE_CH * HIDDEN, be + (size_t)l * HIDDEN, agg);
            mlp_kernel<<<MLP_GRID, 256, 0, stream>>>(
                agg,
                W1 + (size_t)l * HIDDEN * HIDDEN, b1 + (size_t)l * HIDDEN,
                W2 + (size_t)l * HIDDEN * HIDDEN, b2 + (size_t)l * HIDDEN, x);
        }
    }

    batch_out_kernel<<<(N_NODES + 255) / 256, 256, 0, stream>>>(bv, x + (size_t)N_NODES * HIDDEN);
}